// Round 10
// baseline (5441.635 us; speedup 1.0000x reference)
//
#include <hip/hip_runtime.h>
#include <hip/hip_bf16.h>

// Problem dims
#define NB 128   // batch
#define NT 256   // time
#define ND 64    // input dim
#define NL 64    // latent dim
#define NH 256   // hidden
#define NP 4     // scan steps

// 30 MiB static device workspace
__device__ double g_ws[3932160];

static __device__ __forceinline__ double dlapy2_(double x, double y) {
  double ax = fabs(x), ay = fabs(y);
  double w = ax > ay ? ax : ay;
  double z = ax > ay ? ay : ax;
  if (z == 0.0) return w;
  double r = z / w;
  return w * sqrt(1.0 + r * r);
}
static __device__ __forceinline__ double sgn1_(double x) { return copysign(1.0, x); }
static __device__ __forceinline__ void cdiv_(double ar, double ai, double br, double bi,
                                             double& cr, double& ci) {
  if (fabs(br) >= fabs(bi)) {
    double r = bi / br, den = br + r * bi;
    cr = (ar + ai * r) / den;
    ci = (ai - ar * r) / den;
  } else {
    double r = br / bi, den = bi + r * br;
    cr = (ar * r + ai) / den;
    ci = (ai * r - ar) / den;
  }
}
static __device__ __forceinline__ void fwg(float* out, long long ofs, long long lim,
                                           double v) {
  if (ofs >= 0 && ofs < lim) out[ofs] = (float)v;
}
// fast fp64 reciprocal: fp32 rcp seed + 2 Newton steps (~1e-16 rel). Guarded.
static __device__ __forceinline__ double frcp_(double d) {
  float df = (float)d;
  if (df == 0.0f || !isfinite(df)) return 1.0 / d;
  double r = (double)(1.0f / df);
  r = r * (2.0 - d * r);
  r = r * (2.0 - d * r);
  return r;
}
// wave-64 reductions (all lanes get the result)
static __device__ __forceinline__ double wsum_(double v) {
  for (int o = 32; o > 0; o >>= 1) v += __shfl_xor(v, o, 64);
  return v;
}
static __device__ __forceinline__ double wmax_(double v) {
  for (int o = 32; o > 0; o >>= 1) v = fmax(v, __shfl_xor(v, o, 64));
  return v;
}
// Single-wave "barrier": DS ops from one wave are processed in order by the LDS
// unit, so cross-lane LDS communication inside a 64-thread block needs only a
// compiler reordering fence. Zero instructions. (Validated R7-R9.)
static __device__ __forceinline__ void wbar() {
  asm volatile("" ::: "memory");
  __builtin_amdgcn_wave_barrier();
  asm volatile("" ::: "memory");
}

// LAPACK dlanv2: standardize a real 2x2 Schur block
static __device__ void dlanv2_(double& a, double& b, double& c, double& d,
                               double& rt1r, double& rt1i, double& rt2r, double& rt2i,
                               double& cs, double& sn) {
  const double eps = 2.2204460492503131e-16;
  if (c == 0.0) {
    cs = 1.0; sn = 0.0;
  } else if (b == 0.0) {
    cs = 0.0; sn = 1.0;
    double temp = d; d = a; a = temp;
    b = -c; c = 0.0;
  } else if ((a - d) == 0.0 && sgn1_(b) != sgn1_(c)) {
    cs = 1.0; sn = 0.0;
  } else {
    double temp = a - d;
    double p = 0.5 * temp;
    double bcmax = fmax(fabs(b), fabs(c));
    double bcmis = fmin(fabs(b), fabs(c)) * sgn1_(b) * sgn1_(c);
    double scale = fmax(fabs(p), bcmax);
    double z = (p / scale) * p + (bcmax / scale) * bcmis;
    if (z >= 4.0 * eps) {
      z = p + copysign(sqrt(scale) * sqrt(z), p);
      a = d + z;
      d = d - (bcmax / z) * bcmis;
      double tau = dlapy2_(c, z);
      cs = z / tau; sn = c / tau;
      b = b - c; c = 0.0;
    } else {
      double sigma = b + c;
      double tau = dlapy2_(sigma, temp);
      cs = sqrt(0.5 * (1.0 + fabs(sigma) / tau));
      sn = -(p / (tau * cs)) * sgn1_(sigma);
      double aa = a * cs + b * sn, bb = -a * sn + b * cs;
      double cc = c * cs + d * sn, dd = -c * sn + d * cs;
      a = aa * cs + cc * sn; b = bb * cs + dd * sn;
      c = -aa * sn + cc * cs; d = -bb * sn + dd * cs;
      temp = 0.5 * (a + d);
      a = temp; d = temp;
      if (c != 0.0) {
        if (b != 0.0) {
          if (sgn1_(b) == sgn1_(c)) {
            double sab = sqrt(fabs(b)), sac = sqrt(fabs(c));
            double p2 = copysign(sab * sac, c);
            double tau2 = 1.0 / sqrt(fabs(b + c));
            a = temp + p2; d = temp - p2;
            b = b - c; c = 0.0;
            double cs1 = sab * tau2, sn1 = sac * tau2;
            double t0 = cs * cs1 - sn * sn1;
            sn = cs * sn1 + sn * cs1;
            cs = t0;
          }
        } else {
          b = -c; c = 0.0;
          double t0 = cs; cs = -sn; sn = t0;
        }
      }
    }
  }
  rt1r = a; rt2r = d;
  if (c == 0.0) { rt1i = 0.0; rt2i = 0.0; }
  else { rt1i = sqrt(fabs(b)) * sqrt(fabs(c)); rt2i = -rt1i; }
}

// ---------------- encoder only: x -> y (f32 out + f64 ws), fp64 math
__global__ __launch_bounds__(256) void enc_kernel(
    const float* __restrict__ x,
    const float* __restrict__ EW0, const float* __restrict__ EB0,
    const float* __restrict__ EW1, const float* __restrict__ EB1,
    const float* __restrict__ EW2, const float* __restrict__ EB2,
    const float* __restrict__ EW3, const float* __restrict__ EB3,
    float* __restrict__ out_y, double* __restrict__ y64, long long lim)
{
  const int tid = threadIdx.x;
  const long long tok0 = (long long)blockIdx.x * 8;
  __shared__ double xin[8][64];
  __shared__ double h0[8][256];
  __shared__ double h1[8][256];
  for (int idx = tid; idx < 512; idx += 256) {
    int tk = idx >> 6, f2 = idx & 63;
    xin[tk][f2] = (double)x[(tok0 + tk) * 64 + f2];
  }
  __syncthreads();
  { // L1 64->256
    int j = tid; double acc[8]; double bj = (double)EB0[j];
    for (int tk = 0; tk < 8; ++tk) acc[tk] = bj;
#pragma unroll 8
    for (int i2 = 0; i2 < 64; ++i2) {
      double w = (double)EW0[i2 * 256 + j];
      for (int tk = 0; tk < 8; ++tk) acc[tk] += xin[tk][i2] * w;
    }
    for (int tk = 0; tk < 8; ++tk) h0[tk][j] = fmax(acc[tk], 0.0);
  }
  __syncthreads();
  { // L2
    int j = tid; double acc[8]; double bj = (double)EB1[j];
    for (int tk = 0; tk < 8; ++tk) acc[tk] = bj;
#pragma unroll 4
    for (int i2 = 0; i2 < 256; ++i2) {
      double w = (double)EW1[i2 * 256 + j];
      for (int tk = 0; tk < 8; ++tk) acc[tk] += h0[tk][i2] * w;
    }
    for (int tk = 0; tk < 8; ++tk) h1[tk][j] = fmax(acc[tk], 0.0);
  }
  __syncthreads();
  { // L3
    int j = tid; double acc[8]; double bj = (double)EB2[j];
    for (int tk = 0; tk < 8; ++tk) acc[tk] = bj;
#pragma unroll 4
    for (int i2 = 0; i2 < 256; ++i2) {
      double w = (double)EW2[i2 * 256 + j];
      for (int tk = 0; tk < 8; ++tk) acc[tk] += h1[tk][i2] * w;
    }
    for (int tk = 0; tk < 8; ++tk) h0[tk][j] = fmax(acc[tk], 0.0);
  }
  __syncthreads();
  { // L4 256->64 (no relu): y
    int j = tid & 63;
    int tg = tid >> 6;
    double acc0 = (double)EB3[j], acc1 = acc0;
#pragma unroll 4
    for (int i2 = 0; i2 < 256; ++i2) {
      double w = (double)EW3[i2 * 64 + j];
      acc0 += h0[tg * 2][i2] * w;
      acc1 += h0[tg * 2 + 1][i2] * w;
    }
    for (int u = 0; u < 2; ++u) {
      int tk = tg * 2 + u;
      double a = (u == 0) ? acc0 : acc1;
      long long gl = (tok0 + tk) * 64 + j;
      fwg(out_y, gl, lim, a);
      y64[gl] = a;
    }
  }
}

// ---------------- standalone 4-layer decoder on f64 input (for x_adv), fp64
__global__ __launch_bounds__(256) void dec4_kernel(
    const double* __restrict__ inp, long long ntok,
    const float* __restrict__ W0, const float* __restrict__ B0,
    const float* __restrict__ W1, const float* __restrict__ B1,
    const float* __restrict__ W2, const float* __restrict__ B2,
    const float* __restrict__ W3, const float* __restrict__ B3,
    float* __restrict__ outb, long long lim)
{
  const int tid = threadIdx.x;
  const long long tok0 = (long long)blockIdx.x * 8;
  __shared__ double xin[8][64];
  __shared__ double h0[8][256];
  __shared__ double h1[8][256];
  for (int idx = tid; idx < 512; idx += 256) {
    int tk = idx >> 6, f2 = idx & 63;
    long long gl = (tok0 + tk) * 64 + f2;
    xin[tk][f2] = (tok0 + tk < ntok) ? inp[gl] : 0.0;
  }
  __syncthreads();
  {
    int j = tid; double acc[8]; double bj = (double)B0[j];
    for (int tk = 0; tk < 8; ++tk) acc[tk] = bj;
#pragma unroll 8
    for (int i2 = 0; i2 < 64; ++i2) {
      double w = (double)W0[i2 * 256 + j];
      for (int tk = 0; tk < 8; ++tk) acc[tk] += xin[tk][i2] * w;
    }
    for (int tk = 0; tk < 8; ++tk) h0[tk][j] = fmax(acc[tk], 0.0);
  }
  __syncthreads();
  {
    int j = tid; double acc[8]; double bj = (double)B1[j];
    for (int tk = 0; tk < 8; ++tk) acc[tk] = bj;
#pragma unroll 4
    for (int i2 = 0; i2 < 256; ++i2) {
      double w = (double)W1[i2 * 256 + j];
      for (int tk = 0; tk < 8; ++tk) acc[tk] += h0[tk][i2] * w;
    }
    for (int tk = 0; tk < 8; ++tk) h1[tk][j] = fmax(acc[tk], 0.0);
  }
  __syncthreads();
  {
    int j = tid; double acc[8]; double bj = (double)B2[j];
    for (int tk = 0; tk < 8; ++tk) acc[tk] = bj;
#pragma unroll 4
    for (int i2 = 0; i2 < 256; ++i2) {
      double w = (double)W2[i2 * 256 + j];
      for (int tk = 0; tk < 8; ++tk) acc[tk] += h1[tk][i2] * w;
    }
    for (int tk = 0; tk < 8; ++tk) h0[tk][j] = fmax(acc[tk], 0.0);
  }
  __syncthreads();
  {
    int j = tid & 63;
    int tg = tid >> 6;
    double acc0 = (double)B3[j], acc1 = acc0;
#pragma unroll 4
    for (int i2 = 0; i2 < 256; ++i2) {
      double w = (double)W3[i2 * 64 + j];
      acc0 += h0[tg * 2][i2] * w;
      acc1 += h0[tg * 2 + 1][i2] * w;
    }
    for (int u = 0; u < 2; ++u) {
      long long tok = tok0 + tg * 2 + u;
      if (tok < ntok) fwg(outb, tok * 64 + j, lim, (u == 0) ? acc0 : acc1);
    }
  }
}

// ---------------- G = y_m y_m^T, A = y_p y_m^T (per batch), fp64
__global__ __launch_bounds__(256) void buildGA_kernel(const double* __restrict__ y64,
                                                      double* __restrict__ G,
                                                      double* __restrict__ A)
{
  int b = blockIdx.x, tid = threadIdx.x;
  __shared__ double ybuf[65][64];
  const double* yb = y64 + (size_t)b * NT * 64;
  double g[16], a[16];
  for (int s = 0; s < 16; ++s) { g[s] = 0.0; a[s] = 0.0; }
  for (int c0 = 0; c0 < 255; c0 += 64) {
    int nrow = (256 - c0 < 65) ? (256 - c0) : 65;
    for (int idx = tid; idx < nrow * 64; idx += 256) {
      int rr = idx >> 6, f2 = idx & 63;
      ybuf[rr][f2] = yb[(size_t)(c0 + rr) * 64 + f2];
    }
    __syncthreads();
    int tmax = (254 - c0 < 63) ? (254 - c0) : 63;
    for (int s = 0; s < 16; ++s) {
      int id = s * 256 + tid;
      int i2 = id >> 6, j2 = id & 63;
      double gg = g[s], aa = a[s];
      for (int tt = 0; tt <= tmax; ++tt) {
        double yj = ybuf[tt][j2];
        gg += ybuf[tt][i2] * yj;
        aa += ybuf[tt + 1][i2] * yj;
      }
      g[s] = gg; a[s] = aa;
    }
    __syncthreads();
  }
  for (int s = 0; s < 16; ++s) {
    int id = s * 256 + tid;
    G[(size_t)b * 4096 + id] = g[s];
    A[(size_t)b * 4096 + id] = a[s];
  }
}

// ---------------- K = A G^{-1} via Cholesky (G SPD), per batch (single wave)
__global__ __launch_bounds__(64) void cholsolve_kernel(const double* __restrict__ G,
                                                       const double* __restrict__ A,
                                                       double* __restrict__ Km)
{
  int b = blockIdx.x, t = threadIdx.x;
  __shared__ double C[64][65];
  __shared__ double X[64][65];
  const double* Gb = G + (size_t)b * 4096;
  const double* Ab = A + (size_t)b * 4096;
  for (int r = 0; r < 64; ++r) C[r][t] = Gb[r * 64 + t];
  for (int i2 = 0; i2 < 64; ++i2) X[i2][t] = Ab[t * 64 + i2];
  __syncthreads();
  for (int k = 0; k < 64; ++k) {
    double s = C[k][k];
    for (int m2 = 0; m2 < k; ++m2) s -= C[k][m2] * C[k][m2];
    double ckk = sqrt(fmax(s, 1e-300));
    wbar();
    if (t == k) C[k][k] = ckk;
    if (t > k) {
      double v = C[t][k];
      for (int m2 = 0; m2 < k; ++m2) v -= C[t][m2] * C[k][m2];
      C[t][k] = v / ckk;
    }
    wbar();
  }
  for (int i2 = 0; i2 < 64; ++i2) {
    double v = X[i2][t];
    for (int m2 = 0; m2 < i2; ++m2) v -= C[i2][m2] * X[m2][t];
    X[i2][t] = v / C[i2][i2];
  }
  for (int i2 = 63; i2 >= 0; --i2) {
    double v = X[i2][t];
    for (int m2 = i2 + 1; m2 < 64; ++m2) v -= C[m2][i2] * X[m2][t];
    X[i2][t] = v / C[i2][i2];
  }
  wbar();
  for (int i2 = 0; i2 < 64; ++i2)
    Km[(size_t)b * 4096 + (size_t)t * 64 + i2] = X[i2][t];
}

// ---------------- FAT kernel: blocks <128 -> eig; blocks >=128 -> fp32 x_ae decoder
__global__ __launch_bounds__(64) void eig_dec_kernel(
    const double* __restrict__ Kmat,
    double* __restrict__ modes_re, double* __restrict__ modes_im,
    double* __restrict__ klog,
    float* __restrict__ out, long long o_kevals, long long o_kmodes,
    int cplx, long long lim,
    const double* __restrict__ y64,
    const float* __restrict__ DW0, const float* __restrict__ DB0,
    const float* __restrict__ DW1, const float* __restrict__ DB1,
    const float* __restrict__ DW2, const float* __restrict__ DB2,
    const float* __restrict__ DW3, const float* __restrict__ DB3,
    float* __restrict__ out_xae)
{
  const int t = threadIdx.x;
  __shared__ __align__(16) double smem[8704];   // 69632 B, shared by both paths

  if (blockIdx.x >= NB) {
    // ---------- fp32 decoder for x_ae, 8 tokens per block ----------
    const int blk = blockIdx.x - NB;
    const long long tok0 = (long long)blk * 8;
    float (*fx)[64] = (float (*)[64])(smem);
    float (*fh0)[256] = (float (*)[256])(smem + 256);
    float (*fh1)[256] = (float (*)[256])(smem + 1280);
    for (int idx = t; idx < 512; idx += 64) {
      int tk = idx >> 6, f2 = idx & 63;
      fx[tk][f2] = (float)y64[(tok0 + tk) * 64 + f2];
    }
    __syncthreads();
    float acc[4][8];
    for (int s = 0; s < 4; ++s) {
      float bj = DB0[t + 64 * s];
      for (int tk = 0; tk < 8; ++tk) acc[s][tk] = bj;
    }
#pragma unroll 4
    for (int i = 0; i < 64; ++i) {
      float xv[8];
      for (int tk = 0; tk < 8; ++tk) xv[tk] = fx[tk][i];
      for (int s = 0; s < 4; ++s) {
        float w = DW0[i * 256 + t + 64 * s];
        for (int tk = 0; tk < 8; ++tk) acc[s][tk] += xv[tk] * w;
      }
    }
    for (int s = 0; s < 4; ++s)
      for (int tk = 0; tk < 8; ++tk) fh0[tk][t + 64 * s] = fmaxf(acc[s][tk], 0.0f);
    __syncthreads();
    for (int s = 0; s < 4; ++s) {
      float bj = DB1[t + 64 * s];
      for (int tk = 0; tk < 8; ++tk) acc[s][tk] = bj;
    }
#pragma unroll 2
    for (int i = 0; i < 256; ++i) {
      float xv[8];
      for (int tk = 0; tk < 8; ++tk) xv[tk] = fh0[tk][i];
      for (int s = 0; s < 4; ++s) {
        float w = DW1[i * 256 + t + 64 * s];
        for (int tk = 0; tk < 8; ++tk) acc[s][tk] += xv[tk] * w;
      }
    }
    for (int s = 0; s < 4; ++s)
      for (int tk = 0; tk < 8; ++tk) fh1[tk][t + 64 * s] = fmaxf(acc[s][tk], 0.0f);
    __syncthreads();
    for (int s = 0; s < 4; ++s) {
      float bj = DB2[t + 64 * s];
      for (int tk = 0; tk < 8; ++tk) acc[s][tk] = bj;
    }
#pragma unroll 2
    for (int i = 0; i < 256; ++i) {
      float xv[8];
      for (int tk = 0; tk < 8; ++tk) xv[tk] = fh1[tk][i];
      for (int s = 0; s < 4; ++s) {
        float w = DW2[i * 256 + t + 64 * s];
        for (int tk = 0; tk < 8; ++tk) acc[s][tk] += xv[tk] * w;
      }
    }
    for (int s = 0; s < 4; ++s)
      for (int tk = 0; tk < 8; ++tk) fh0[tk][t + 64 * s] = fmaxf(acc[s][tk], 0.0f);
    __syncthreads();
    float a4[8];
    float bj3 = DB3[t];
    for (int tk = 0; tk < 8; ++tk) a4[tk] = bj3;
#pragma unroll 2
    for (int i = 0; i < 256; ++i) {
      float w = DW3[i * 64 + t];
      for (int tk = 0; tk < 8; ++tk) a4[tk] += fh0[tk][i] * w;
    }
    for (int tk = 0; tk < 8; ++tk)
      fwg(out_xae, (tok0 + tk) * 64 + t, lim, (double)a4[tk]);
    return;
  }

  // ---------- eig path (blocks 0..127, single wave) ----------
  const int b = blockIdx.x;
  double (*Hs)[65] = (double (*)[65])smem;           // 4160 doubles
  double (*Zs)[65] = (double (*)[65])(smem + 4160);  // 4160 doubles, Zs[col][row]
  double* wr = smem + 8320;
  double* wi = wr + 64;
  double* bscale = wi + 64;
  double* tau = bscale + 64;
  double* xr = tau + 64;
  double* xi = xr + 64;
  double* mre = modes_re + (size_t)b * 4096;  // row-major [row*64+col]
  double* mim = modes_im + (size_t)b * 4096;

  const double ulp = 2.2204460492503131e-16;
  const double safmin = 2.2250738585072014e-308;

  for (int r = 0; r < 64; ++r) Hs[r][t] = Kmat[(size_t)b * 4096 + r * 64 + t];
  bscale[t] = 1.0;
  __syncthreads();

  // ---- dgebal scaling
  {
    const double sclfac = 2.0, factor = 0.95;
    const double sfmin1 = safmin / ulp;
    const double sfmax1 = 1.0 / sfmin1;
    const double sfmin2 = sfmin1 * sclfac;
    const double sfmax2 = 1.0 / sfmin2;
    for (int sweep = 0; sweep < 64; ++sweep) {
      bool noconv = false;
      for (int i = 0; i < 64; ++i) {
        double colv = fabs(Hs[t][i]);
        double rowv = fabs(Hs[i][t]);
        double c = wsum_((t == i) ? 0.0 : colv);
        double r = wsum_((t == i) ? 0.0 : rowv);
        double ca = wmax_(colv);
        double ra = wmax_(rowv);
        if (c == 0.0 || r == 0.0) continue;
        double g = r / sclfac, f = 1.0, s = c + r;
        while (c < g) {
          if (fmax(fmax(f, c), ca) >= sfmax2 || fmin(fmin(r, g), ra) <= sfmin2) break;
          f *= sclfac; c *= sclfac; ca *= sclfac;
          r /= sclfac; g /= sclfac; ra /= sclfac;
        }
        g = c / sclfac;
        while (g >= r) {
          if (fmax(r, ra) >= sfmax2 || fmin(fmin(fmin(f, c), g), ca) <= sfmin2) break;
          f /= sclfac; c /= sclfac; g /= sclfac; ca /= sclfac;
          r *= sclfac; ra *= sclfac;
        }
        if (c + r >= factor * s) continue;
        double bsi = bscale[i];
        if (f < 1.0 && bsi < 1.0) { if (f * bsi <= sfmin1) continue; }
        if (f > 1.0 && bsi > 1.0) { if (bsi >= sfmax1 / f) continue; }
        double gi = 1.0 / f;
        Hs[i][t] *= gi;
        Hs[t][i] *= f;
        if (t == 0) bscale[i] = bsi * f;
        noconv = true;
        wbar();
      }
      if (!noconv) break;
    }
    wbar();
  }

  // ---- dgehd2
  for (int i = 0; i < 62; ++i) {
    double alpha = Hs[i + 1][i];
    double contrib = (t >= i + 2) ? Hs[t][i] * Hs[t][i] : 0.0;
    double ss = wsum_(contrib);
    double taui, beta;
    if (ss == 0.0) {
      taui = 0.0; beta = alpha;
    } else {
      beta = -copysign(sqrt(alpha * alpha + ss), alpha);
      taui = (beta - alpha) / beta;
      double sc = 1.0 / (alpha - beta);
      if (t >= i + 2) Hs[t][i] *= sc;
    }
    if (t == 0) { tau[i] = taui; Hs[i + 1][i] = beta; }
    wbar();
    if (taui != 0.0) {
      {
        double sum = Hs[t][i + 1];
        for (int k = i + 2; k < 64; ++k) sum += Hs[t][k] * Hs[k][i];
        sum *= taui;
        Hs[t][i + 1] -= sum;
        for (int k = i + 2; k < 64; ++k) Hs[t][k] -= sum * Hs[k][i];
      }
      wbar();
      if (t >= i + 1) {
        double sum = Hs[i + 1][t];
        for (int k = i + 2; k < 64; ++k) sum += Hs[k][i] * Hs[k][t];
        sum *= taui;
        Hs[i + 1][t] -= sum;
        for (int k = i + 2; k < 64; ++k) Hs[k][t] -= sum * Hs[k][i];
      }
      wbar();
    }
  }

  // ---- dorghr: Zs[col][row], lane t owns column t
  {
    for (int r = 0; r < 64; ++r) Zs[t][r] = (r == t) ? 1.0 : 0.0;
    for (int i = 61; i >= 0; --i) {
      double taui = tau[i];
      if (taui != 0.0) {
        double sum = Zs[t][i + 1];
        for (int k = i + 2; k < 64; ++k) sum += Hs[k][i] * Zs[t][k];
        sum *= taui;
        Zs[t][i + 1] -= sum;
        for (int k = i + 2; k < 64; ++k) Zs[t][k] -= sum * Hs[k][i];
      }
    }
  }
  wbar();
  for (int r = t + 2; r < 64; ++r) Hs[r][t] = 0.0;
  __syncthreads();

  // ---- dlahqr (wantt, wantz)
  {
    const int lo = 0, hi = 63;
    const double dat1 = 0.75, dat2 = -0.4375;
    const int kexsh = 10;
    const double smlnum = safmin * (64.0 / ulp);
    int I = hi;
    int kdefl = 0;
    while (I >= lo) {
      int L = lo;
      bool done = false;
      const int itmax = 30 * 64;
      for (int its = 0; its <= itmax; ++its) {
        int k;
        {
          bool pred = false;
          int kl = t;
          if (kl > L && kl <= I) {
            double sub = fabs(Hs[kl][kl - 1]);
            if (sub <= smlnum) pred = true;
            else {
              double tst = fabs(Hs[kl - 1][kl - 1]) + fabs(Hs[kl][kl]);
              if (tst == 0.0) {
                if (kl - 2 >= lo) tst += fabs(Hs[kl - 1][kl - 2]);
                if (kl + 1 <= hi) tst += fabs(Hs[kl + 1][kl]);
              }
              if (sub <= ulp * tst) {
                double h12a = fabs(Hs[kl - 1][kl]);
                double ab = fmax(sub, h12a), ba = fmin(sub, h12a);
                double hkk = fabs(Hs[kl][kl]);
                double dif = fabs(Hs[kl - 1][kl - 1] - Hs[kl][kl]);
                double aa = fmax(hkk, dif), bb2 = fmin(hkk, dif);
                double s = aa + ab;
                if (ba * (ab / s) <= fmax(smlnum, ulp * (bb2 * (aa / s)))) pred = true;
              }
            }
          }
          unsigned long long msk = __ballot(pred);
          k = msk ? (63 - __builtin_clzll(msk)) : L;
        }
        L = k;
        if (L > lo) { if (t == 0) Hs[L][L - 1] = 0.0; }
        wbar();
        if (L >= I - 1) { done = true; break; }
        kdefl++;
        double h11, h12, h21, h22;
        if (kdefl % (2 * kexsh) == 0) {
          double s = dat1 * (fabs(Hs[I][I - 1]) + fabs(Hs[I - 1][I - 2]));
          h11 = dat2 * s + Hs[I][I]; h12 = s; h21 = s; h22 = h11;
        } else if (kdefl % kexsh == 0) {
          double s = dat1 * (fabs(Hs[L + 1][L]) + fabs(Hs[L + 2][L + 1]));
          h11 = dat2 * s + Hs[L][L]; h12 = s; h21 = s; h22 = h11;
        } else {
          h11 = Hs[I - 1][I - 1]; h21 = Hs[I][I - 1];
          h12 = Hs[I - 1][I];     h22 = Hs[I][I];
        }
        double rt1r, rt1i, rt2r, rt2i;
        {
          double s = fabs(h11) + fabs(h12) + fabs(h21) + fabs(h22);
          if (s == 0.0) { rt1r = rt1i = rt2r = rt2i = 0.0; }
          else {
            double a_ = h11 / s, c_ = h21 / s, b_ = h12 / s, d_ = h22 / s;
            double tr = a_ + d_;
            double det = (a_ - d_) * (a_ - d_) * 0.25 + b_ * c_;
            if (det >= 0.0) {
              double rtdisc = sqrt(det);
              double r1 = tr * 0.5 + rtdisc;
              double r2 = tr * 0.5 - rtdisc;
              double pick = (fabs(r1 - d_) <= fabs(r2 - d_)) ? r1 : r2;
              rt1r = pick * s; rt2r = rt1r; rt1i = 0.0; rt2i = 0.0;
            } else {
              rt1r = tr * 0.5 * s; rt2r = rt1r;
              rt1i = sqrt(-det) * s; rt2i = -rt1i;
            }
          }
        }
        int m; double v0, v1, v2;
        {
          double w0 = 0.0, w1 = 0.0, w2 = 0.0;
          bool ok = false;
          int mm = t;
          if (mm >= L && mm <= I - 2) {
            double h21s = Hs[mm + 1][mm];
            double s = fabs(Hs[mm][mm] - rt2r) + fabs(rt2i) + fabs(h21s);
            h21s = Hs[mm + 1][mm] / s;
            w0 = h21s * Hs[mm][mm + 1] + (Hs[mm][mm] - rt1r) * ((Hs[mm][mm] - rt2r) / s)
                 - rt1i * (rt2i / s);
            w1 = h21s * (Hs[mm][mm] + Hs[mm + 1][mm + 1] - rt1r - rt2r);
            w2 = h21s * Hs[mm + 2][mm + 1];
            double s2 = fabs(w0) + fabs(w1) + fabs(w2);
            w0 /= s2; w1 /= s2; w2 /= s2;
            if (mm == L) ok = true;
            else ok = (fabs(Hs[mm][mm - 1]) * (fabs(w1) + fabs(w2)) <=
                       ulp * fabs(w0) *
                           (fabs(Hs[mm - 1][mm - 1]) + fabs(Hs[mm][mm]) +
                            fabs(Hs[mm + 1][mm + 1])));
          }
          unsigned long long msk = __ballot(ok);
          m = 63 - __builtin_clzll(msk);
          v0 = __shfl(w0, m); v1 = __shfl(w1, m); v2 = __shfl(w2, m);
        }
        // ---- bulge chase: pipelined next-u (no cross-lane round-trip on the
        // u-carry path). next-u computed from phase-A registers (n1,n2 shfls,
        // issued early, consumed next step) + lane kk+3's pre-step preview.
        double nu0 = 0.0, nu1 = 0.0, nu2 = 0.0;
        double zc0 = 0.0, zc1 = 0.0;
        for (int kk = m; kk <= I - 1; ++kk) {
          int nr = (3 < I - kk + 1) ? 3 : (I - kk + 1);
          // preloads (all off the dependency chain; latency hides under dlarfg)
          double a0 = Hs[kk][t];
          double a1 = Hs[kk + 1][t];
          double a2 = (nr == 3) ? Hs[kk + 2][t] : 0.0;
          double p0 = Hs[t][kk];
          double p1 = Hs[t][kk + 1];
          double p2 = (nr == 3) ? Hs[t][kk + 2] : 0.0;
          double z0, z1;
          if (kk > m) { z0 = zc0; z1 = zc1; }
          else { z0 = Zs[kk][t]; z1 = Zs[kk + 1][t]; }
          double z2 = (nr == 3) ? Zs[kk + 2][t] : 0.0;
          double u0, u1, u2 = 0.0;
          if (kk > m) { u0 = nu0; u1 = nu1; u2 = (nr == 3) ? nu2 : 0.0; }
          else        { u0 = v0;  u1 = v1;  u2 = (nr == 3) ? v2 : 0.0; }
          double t1;
          {  // dlarfg, plain sqrt + fast reciprocals
            double xn2 = u1 * u1 + u2 * u2;
            if (xn2 == 0.0) t1 = 0.0;
            else {
              double beta = -copysign(sqrt(u0 * u0 + xn2), u0);
              t1 = (beta - u0) * frcp_(beta);
              double sc = frcp_(u0 - beta);
              u1 *= sc; u2 *= sc;
              u0 = beta;
            }
          }
          double t2 = t1 * u1, t3 = t1 * u2;
          // phase A: left(row) update in registers (computed on all lanes;
          // written for t>=kk) + reflector storage
          double sA = a0 + u1 * a1 + u2 * a2;
          double n0 = a0 - sA * t1;
          double n1 = a1 - sA * t2;
          double n2 = a2 - sA * t3;
          if (t >= kk) {
            Hs[kk][t] = n0;
            Hs[kk + 1][t] = n1;
            if (nr == 3) Hs[kk + 2][t] = n2;
          }
          if (t == 0) {
            if (kk > m) {
              Hs[kk][kk - 1] = u0;
              Hs[kk + 1][kk - 1] = 0.0;
              if (kk < I - 1) Hs[kk + 2][kk - 1] = 0.0;
            } else if (m > L) {
              Hs[kk][kk - 1] *= (1.0 - t1);
            }
          }
          // ---- next-u (only meaningful when kk < I-1); shfls issued here,
          // consumed at next step's dlarfg (latency fully hidden).
          {
            int sk2 = (kk + 2 < 64) ? kk + 2 : 63;
            int sk3 = (kk + 3 < 64) ? kk + 3 : 63;
            // lane kk+3's phase-B preview from PRE-step values (out-of-band)
            double prevw = p0 - (p0 + u1 * p1 + u2 * p2) * t1;
            double n1a = __shfl(n1, kk, 64), n1b = __shfl(n1, kk + 1, 64),
                   n1c = __shfl(n1, sk2, 64);
            double n2a = __shfl(n2, kk, 64), n2b = __shfl(n2, kk + 1, 64),
                   n2c = __shfl(n2, sk2, 64);
            nu0 = n1a - (n1a + u1 * n1b + u2 * n1c) * t1;   // = Hs[kk+1][kk] post-B
            nu1 = n2a - (n2a + u1 * n2b + u2 * n2c) * t1;   // = Hs[kk+2][kk] post-B
            nu2 = __shfl(prevw, sk3, 64);                    // = Hs[kk+3][kk] post-B
          }
          wbar();
          // phase B: right(col) update (post-fence reads, identical to R9) + Z
          int rmax = (kk + 3 < I) ? kk + 3 : I;
          if (t <= rmax) {
            double b0 = Hs[t][kk], b1 = Hs[t][kk + 1];
            double b2 = (nr == 3) ? Hs[t][kk + 2] : 0.0;
            double sB = b0 + u1 * b1 + u2 * b2;
            Hs[t][kk] = b0 - sB * t1;
            Hs[t][kk + 1] = b1 - sB * t2;
            if (nr == 3) Hs[t][kk + 2] = b2 - sB * t3;
          }
          {
            double sZ = z0 + u1 * z1 + u2 * z2;
            Zs[kk][t] = z0 - sZ * t1;
            zc0 = z1 - sZ * t2;
            Zs[kk + 1][t] = zc0;
            if (nr == 3) {
              zc1 = z2 - sZ * t3;
              Zs[kk + 2][t] = zc1;
            }
          }
          wbar();
        }
      } // its
      if (!done) {  // failsafe
        wbar();
        if (t == 0) {
          for (int r = lo; r <= I; ++r) { wr[r] = Hs[r][r]; wi[r] = 0.0; }
        }
        wbar();
        I = lo - 1;
        kdefl = 0;
        continue;
      }
      if (L == I) {
        if (t == 0) { wr[I] = Hs[I][I]; wi[I] = 0.0; }
        wbar();
      } else {  // 2x2 block: dlanv2 + rotations
        double a_ = Hs[I - 1][I - 1], b_ = Hs[I - 1][I];
        double c_ = Hs[I][I - 1],     d_ = Hs[I][I];
        double r1r, r1i, r2r, r2i, cs, sn;
        dlanv2_(a_, b_, c_, d_, r1r, r1i, r2r, r2i, cs, sn);
        wbar();
        if (t == 0) {
          Hs[I - 1][I - 1] = a_; Hs[I - 1][I] = b_;
          Hs[I][I - 1] = c_;     Hs[I][I] = d_;
          wr[I - 1] = r1r; wi[I - 1] = r1i;
          wr[I] = r2r;     wi[I] = r2i;
        }
        wbar();
        if (t > I) {
          double x = Hs[I - 1][t], y = Hs[I][t];
          Hs[I - 1][t] = cs * x + sn * y;
          Hs[I][t] = cs * y - sn * x;
        }
        if (t < I - 1) {
          double x = Hs[t][I - 1], y = Hs[t][I];
          Hs[t][I - 1] = cs * x + sn * y;
          Hs[t][I] = cs * y - sn * x;
        }
        {
          double x = Zs[I - 1][t], y = Zs[I][t];
          Zs[I - 1][t] = cs * x + sn * y;
          Zs[I][t] = cs * y - sn * x;
        }
        wbar();
      }
      kdefl = 0;
      I = L - 1;
    }
  }
  __syncthreads();

  // ---- dtrevc + dgebak + normalization
  const double smln = safmin * (64.0 / ulp);
  int ki = 63;
  while (ki >= 0) {
    wbar();
    bool pair = (ki > 0) && (Hs[ki][ki - 1] != 0.0);
    if (!pair) {
      double lam = wr[ki];
      double smin = fmax(ulp * fabs(lam), smln);
      xr[t] = (t < ki) ? -Hs[t][ki] : ((t == ki) ? 1.0 : 0.0);
      wbar();
      int j = ki - 1;
      while (j >= 0) {
        bool blk2 = (j > 0) && (Hs[j][j - 1] != 0.0);
        if (!blk2) {
          double den = Hs[j][j] - lam;
          if (fabs(den) < smin) den = smin;
          double xj = xr[j] / den;
          if (t == j) xr[j] = xj;
          else if (t < j) xr[t] -= xj * Hs[t][j];
          wbar();
          j -= 1;
        } else {
          double t11 = Hs[j - 1][j - 1] - lam, t12 = Hs[j - 1][j];
          double t21 = Hs[j][j - 1], t22 = Hs[j][j] - lam;
          double det = t11 * t22 - t12 * t21;
          if (fabs(det) < smin * smin) det = copysign(smin * smin, (det == 0.0) ? 1.0 : det);
          double b1 = xr[j - 1], b2 = xr[j];
          double x1 = (b1 * t22 - t12 * b2) / det;
          double x2 = (t11 * b2 - t21 * b1) / det;
          if (t == j - 1) xr[j - 1] = x1;
          else if (t == j) xr[j] = x2;
          else if (t < j - 1) xr[t] -= x1 * Hs[t][j - 1] + x2 * Hs[t][j];
          wbar();
          j -= 2;
        }
      }
      double acc = 0.0;
      for (int k2 = 0; k2 <= ki; ++k2) acc += Zs[k2][t] * xr[k2];
      acc *= bscale[t];
      double nn = wsum_(acc * acc);
      double scl = 1.0 / sqrt(nn);
      mre[t * 64 + ki] = acc * scl;
      mim[t * 64 + ki] = 0.0;
      ki -= 1;
    } else {
      double wre = Hs[ki][ki];
      double wim = sqrt(fabs(Hs[ki][ki - 1])) * sqrt(fabs(Hs[ki - 1][ki]));
      double smin = fmax(ulp * (fabs(wre) + wim), smln);
      double seed_r_km1, seed_i_k;
      if (fabs(Hs[ki - 1][ki]) >= fabs(Hs[ki][ki - 1])) {
        seed_r_km1 = 1.0;
        seed_i_k = wim / Hs[ki - 1][ki];
      } else {
        seed_r_km1 = -wim / Hs[ki][ki - 1];
        seed_i_k = 1.0;
      }
      if (t < ki - 1) {
        xr[t] = -seed_r_km1 * Hs[t][ki - 1];
        xi[t] = -seed_i_k * Hs[t][ki];
      } else if (t == ki - 1) { xr[t] = seed_r_km1; xi[t] = 0.0; }
      else if (t == ki) { xr[t] = 0.0; xi[t] = seed_i_k; }
      else { xr[t] = 0.0; xi[t] = 0.0; }
      wbar();
      int j = ki - 2;
      while (j >= 0) {
        bool blk2 = (j > 0) && (Hs[j][j - 1] != 0.0);
        if (!blk2) {
          double dr = Hs[j][j] - wre, di = -wim;
          if (fabs(dr) + fabs(di) < smin) { dr = smin; di = 0.0; }
          double xjr, xji;
          cdiv_(xr[j], xi[j], dr, di, xjr, xji);
          if (t == j) { xr[j] = xjr; xi[j] = xji; }
          else if (t < j) {
            xr[t] -= xjr * Hs[t][j];
            xi[t] -= xji * Hs[t][j];
          }
          wbar();
          j -= 1;
        } else {
          double t11 = Hs[j - 1][j - 1] - wre, t12 = Hs[j - 1][j];
          double t21 = Hs[j][j - 1], t22 = Hs[j][j] - wre;
          double detr = t11 * t22 - wim * wim - t12 * t21;
          double deti = -wim * (t11 + t22);
          double b1r = xr[j - 1], b1i = xi[j - 1];
          double b2r = xr[j], b2i = xi[j];
          double n1r = b1r * t22 + b1i * wim - t12 * b2r;
          double n1i = b1i * t22 - b1r * wim - t12 * b2i;
          double n2r = t11 * b2r + b2i * wim - t21 * b1r;
          double n2i = t11 * b2i - b2r * wim - t21 * b1i;
          double x1r, x1i, x2r, x2i;
          cdiv_(n1r, n1i, detr, deti, x1r, x1i);
          cdiv_(n2r, n2i, detr, deti, x2r, x2i);
          if (t == j - 1) { xr[t] = x1r; xi[t] = x1i; }
          else if (t == j) { xr[t] = x2r; xi[t] = x2i; }
          else if (t < j - 1) {
            xr[t] -= x1r * Hs[t][j - 1] + x2r * Hs[t][j];
            xi[t] -= x1i * Hs[t][j - 1] + x2i * Hs[t][j];
          }
          wbar();
          j -= 2;
        }
      }
      double ar = 0.0, ai = 0.0;
      for (int k2 = 0; k2 <= ki; ++k2) {
        double z = Zs[k2][t];
        ar += z * xr[k2];
        ai += z * xi[k2];
      }
      ar *= bscale[t]; ai *= bscale[t];
      double n2a = wsum_(ar * ar), n2b = wsum_(ai * ai);
      double scl = 1.0 / dlapy2_(sqrt(n2a), sqrt(n2b));
      double vr0 = ar * scl, vi0 = ai * scl;
      double mm = vr0 * vr0 + vi0 * vi0;
      double mmax = wmax_(mm);
      unsigned long long msk = __ballot(mm == mmax);
      int kmx = __ffsll((unsigned long long)msk) - 1;
      double f = __shfl(vr0, kmx), g = __shfl(vi0, kmx);
      double cs_, sn_;
      if (g == 0.0) { cs_ = 1.0; sn_ = 0.0; }
      else if (f == 0.0) { cs_ = 0.0; sn_ = sgn1_(g); }
      else {
        double dd = sqrt(f * f + g * g);
        double sg = sgn1_(f);
        cs_ = fabs(f) / dd;
        sn_ = sg * g / dd;
      }
      double nr0 = cs_ * vr0 + sn_ * vi0;
      double ni0 = cs_ * vi0 - sn_ * vr0;
      if (t == kmx) ni0 = 0.0;
      mre[t * 64 + (ki - 1)] = nr0;
      mim[t * 64 + (ki - 1)] = ni0;
      mre[t * 64 + ki] = nr0;
      mim[t * 64 + ki] = -ni0;
      ki -= 2;
    }
  }

  // ---- k_evals = log(lambda) and outputs
  {
    double er = wr[t], ei = wi[t];
    double lr = log(dlapy2_(er, ei));
    double li = atan2(ei, er);
    klog[(size_t)b * 128 + 2 * t] = lr;
    klog[(size_t)b * 128 + 2 * t + 1] = li;
    if (cplx) {
      fwg(out, o_kevals + ((long long)b * 64 + t) * 2, lim, lr);
      fwg(out, o_kevals + ((long long)b * 64 + t) * 2 + 1, lim, li);
    } else {
      fwg(out, o_kevals + (long long)b * 64 + t, lim, lr);
    }
  }
  for (int k2 = 0; k2 < 64; ++k2) {
    long long idx = ((long long)b * 64 + t) * 64 + k2;
    if (cplx) {
      fwg(out, o_kmodes + idx * 2, lim, mre[t * 64 + k2]);
      fwg(out, o_kmodes + idx * 2 + 1, lim, mim[t * 64 + k2]);
    } else {
      fwg(out, o_kmodes + idx, lim, mre[t * 64 + k2]);
    }
  }
}

// ---------------- complex LU with |re|+|im| partial pivoting (single wave)
__global__ __launch_bounds__(64) void lu_kernel(
    const double* __restrict__ mre, const double* __restrict__ mim,
    double* __restrict__ lure, double* __restrict__ luim, int* __restrict__ piv)
{
  int b = blockIdx.x, t = threadIdx.x;
  __shared__ double Lre[64][65], Lim[64][65];
  for (int r = 0; r < 64; ++r) {
    Lre[r][t] = mre[(size_t)b * 4096 + r * 64 + t];
    Lim[r][t] = mim[(size_t)b * 4096 + r * 64 + t];
  }
  __syncthreads();
  for (int k = 0; k < 64; ++k) {
    double mval = (t >= k) ? (fabs(Lre[t][k]) + fabs(Lim[t][k])) : -1.0;
    double mmax = wmax_(mval);
    unsigned long long msk = __ballot(mval == mmax);
    int p = __ffsll(msk) - 1;
    if (t == 0) piv[b * 64 + k] = p;
    if (p != k) {
      double a0 = Lre[k][t], a1 = Lim[k][t];
      Lre[k][t] = Lre[p][t]; Lim[k][t] = Lim[p][t];
      Lre[p][t] = a0; Lim[p][t] = a1;
    }
    wbar();
    double pr = Lre[k][k], pi = Lim[k][k];
    if (t > k) {
      double lr, li;
      cdiv_(Lre[t][k], Lim[t][k], pr, pi, lr, li);
      Lre[t][k] = lr; Lim[t][k] = li;
      for (int c = k + 1; c < 64; ++c) {
        double ur = Lre[k][c], ui = Lim[k][c];
        Lre[t][c] -= lr * ur - li * ui;
        Lim[t][c] -= lr * ui + li * ur;
      }
    }
    wbar();
  }
  for (int r = 0; r < 64; ++r) {
    lure[(size_t)b * 4096 + r * 64 + t] = Lre[r][t];
    luim[(size_t)b * 4096 + r * 64 + t] = Lim[r][t];
  }
}

// ---------------- solve modes * X = x^T per batch (256 RHS, 4 chunks of 64)
__global__ __launch_bounds__(64) void lusolve_kernel(
    const double* __restrict__ lure, const double* __restrict__ luim,
    const int* __restrict__ piv, const float* __restrict__ x_in,
    float* __restrict__ out, long long o_kefuns, int cplx,
    double* __restrict__ xint, long long lim)
{
  int b = blockIdx.x >> 2;
  int chunk = blockIdx.x & 3;
  int t = threadIdx.x;
  int tglob = chunk * 64 + t;
  __shared__ double br_[64][64], bi_[64][64];
  const double* Lr = lure + (size_t)b * 4096;
  const double* Li = luim + (size_t)b * 4096;
  for (int i2 = 0; i2 < 64; ++i2) {
    br_[i2][t] = (double)x_in[((size_t)b * 256 + tglob) * 64 + i2];
    bi_[i2][t] = 0.0;
  }
  const int* pv = piv + b * 64;
  for (int k = 0; k < 64; ++k) {
    int p = pv[k];
    if (p != k) {
      double a0 = br_[k][t], a1 = bi_[k][t];
      br_[k][t] = br_[p][t]; bi_[k][t] = bi_[p][t];
      br_[p][t] = a0; bi_[p][t] = a1;
    }
  }
  for (int k = 0; k < 63; ++k) {
    double bkr = br_[k][t], bki = bi_[k][t];
    for (int i2 = k + 1; i2 < 64; ++i2) {
      double lr = Lr[i2 * 64 + k], li = Li[i2 * 64 + k];
      br_[i2][t] -= lr * bkr - li * bki;
      bi_[i2][t] -= lr * bki + li * bkr;
    }
  }
  for (int k = 63; k >= 0; --k) {
    double xr0, xi0;
    cdiv_(br_[k][t], bi_[k][t], Lr[k * 64 + k], Li[k * 64 + k], xr0, xi0);
    br_[k][t] = xr0; bi_[k][t] = xi0;
    for (int i2 = 0; i2 < k; ++i2) {
      double ur = Lr[i2 * 64 + k], ui = Li[i2 * 64 + k];
      br_[i2][t] -= ur * xr0 - ui * xi0;
      bi_[i2][t] -= ur * xi0 + ui * xr0;
    }
  }
  for (int i2 = 0; i2 < 64; ++i2) {
    long long idx = ((long long)b * 64 + i2) * 256 + tglob;
    if (cplx) {
      fwg(out, o_kefuns + idx * 2, lim, br_[i2][t]);
      fwg(out, o_kefuns + idx * 2 + 1, lim, bi_[i2][t]);
    } else {
      fwg(out, o_kefuns + idx, lim, br_[i2][t]);
    }
  }
  if (tglob == 255) {
    for (int i2 = 0; i2 < 64; ++i2) {
      xint[(size_t)b * 128 + 2 * i2] = br_[i2][t];
      xint[(size_t)b * 128 + 2 * i2 + 1] = bi_[i2][t];
    }
  }
}

// ---------------- y_pred scan
__global__ __launch_bounds__(64) void ypred_kernel(
    const double* __restrict__ klog, const double* __restrict__ xint,
    const double* __restrict__ mre, const double* __restrict__ mim,
    float* __restrict__ out, long long o_yadvr, long long o_yadvi,
    double* __restrict__ yadv64, long long lim)
{
  int b = blockIdx.x, t = threadIdx.x;
  __shared__ double er[64], ei[64], wxr[64], wxi[64];
  double kr = klog[(size_t)b * 128 + 2 * t], kiv = klog[(size_t)b * 128 + 2 * t + 1];
  er[t] = kr * kr - kiv * kiv;
  ei[t] = 2.0 * kr * kiv;
  double xr0 = xint[(size_t)b * 128 + 2 * t], xi0 = xint[(size_t)b * 128 + 2 * t + 1];
  __syncthreads();
  for (int p = 0; p < 4; ++p) {
    wxr[t] = er[t] * xr0 - ei[t] * xi0;
    wxi[t] = er[t] * xi0 + ei[t] * xr0;
    __syncthreads();
    double ar = 0.0, ai = 0.0;
    const double* mr = mre + (size_t)b * 4096 + (size_t)t * 64;
    const double* mi = mim + (size_t)b * 4096 + (size_t)t * 64;
    for (int k = 0; k < 64; ++k) {
      double wr0 = wxr[k], wi0 = wxi[k];
      ar += mr[k] * wr0 - mi[k] * wi0;
      ai += mr[k] * wi0 + mi[k] * wr0;
    }
    long long idx = ((long long)b * 4 + p) * 64 + t;
    fwg(out, o_yadvr + idx, lim, ar);
    fwg(out, o_yadvi + idx, lim, ai);
    yadv64[idx] = ar;
    double e2r = er[t] * er[t] - ei[t] * ei[t];
    double e2i = 2.0 * er[t] * ei[t];
    __syncthreads();
    er[t] = e2r; ei[t] = e2i;
    __syncthreads();
  }
}

extern "C" void kernel_launch(void* const* d_in, const int* in_sizes, int n_in,
                              void* d_out, int out_size, void* d_ws, size_t ws_size,
                              hipStream_t stream) {
  (void)in_sizes; (void)n_in; (void)d_ws; (void)ws_size;
  const float* x = (const float*)d_in[0];
  const float* ew0 = (const float*)d_in[1];  const float* eb0 = (const float*)d_in[2];
  const float* ew1 = (const float*)d_in[3];  const float* eb1 = (const float*)d_in[4];
  const float* ew2 = (const float*)d_in[5];  const float* eb2 = (const float*)d_in[6];
  const float* ew3 = (const float*)d_in[7];  const float* eb3 = (const float*)d_in[8];
  const float* dw0 = (const float*)d_in[9];  const float* db0 = (const float*)d_in[10];
  const float* dw1 = (const float*)d_in[11]; const float* db1 = (const float*)d_in[12];
  const float* dw2 = (const float*)d_in[13]; const float* db2 = (const float*)d_in[14];
  const float* dw3 = (const float*)d_in[15]; const float* db3 = (const float*)d_in[16];
  float* out = (float*)d_out;   // output dtype is FLOAT32
  const long long lim = (long long)out_size;

  void* wsp = nullptr;
  hipGetSymbolAddress(&wsp, HIP_SYMBOL(g_ws));
  char* ws = (char*)wsp;
  // Alias audit (per-kernel live sets, all disjoint):
  double* y64  = (double*)(ws + 0);            // [0,16M)   k1 -> eig_dec(decoder)
  double* G    = (double*)(ws + 16777216);     // [16,20M)  k2 -> k3
  double* A    = (double*)(ws + 20971520);     // [20,24M)  k2 -> k3
  double* Km   = (double*)(ws + 25165824);     // [24,28M)  k3 -> k4
  double* mre  = (double*)(ws + 16777216);     // [16,20M)  k4 -> k7 (G dead)
  double* mim  = (double*)(ws + 20971520);     // [20,24M)  k4 -> k7 (A dead)
  double* lure = (double*)(ws + 25165824);     // [24,28M)  k5 -> k6 (Km dead)
  double* luim = (double*)(ws + 0);            // [0,4M)    k5 -> k6 (y64 dead)
  double* klog = (double*)(ws + 29360128);     // +128K     k4 -> k7
  double* xint = (double*)(ws + 29491200);     // +128K     k6 -> k7
  double* yadv = (double*)(ws + 29622272);     // +256K     k7 -> k8
  int*    piv  = (int*)   (ws + 29884416);     // +32K      k5 -> k6

  const long long n_y = 2097152, n_s = 32768;
  int cplx = (out_size > 8000000) ? 1 : 0;
  long long o_y = 0, o_xae = n_y, o_xadv = 2 * n_y;
  long long o_yadvr = o_xadv + n_s, o_yadvi = o_yadvr + n_s;
  long long o_kevals = o_yadvi + n_s;
  long long o_kefuns, o_kmodes;
  if (cplx) { o_kefuns = o_kevals + 2 * 8192;  o_kmodes = o_kefuns + 2 * 2097152; }
  else      { o_kefuns = o_kevals + 8192;      o_kmodes = o_kefuns + 2097152; }

  // k1) encoder: y (f32 + f64)
  enc_kernel<<<4096, 256, 0, stream>>>(x,
      ew0, eb0, ew1, eb1, ew2, eb2, ew3, eb3, out + o_y, y64, lim);
  // k2) G = y_m y_m^T, A = y_p y_m^T
  buildGA_kernel<<<128, 256, 0, stream>>>(y64, G, A);
  // k3) K = A G^{-1}
  cholsolve_kernel<<<128, 64, 0, stream>>>(G, A, Km);
  // k4) FAT: eig(K) on blocks 0..127  ||  fp32 x_ae decoder on blocks 128..4223
  eig_dec_kernel<<<128 + 4096, 64, 0, stream>>>(Km, mre, mim, klog,
      out, o_kevals, o_kmodes, cplx, lim,
      y64, dw0, db0, dw1, db1, dw2, db2, dw3, db3, out + o_xae);
  // k5) LU(modes)
  lu_kernel<<<128, 64, 0, stream>>>(mre, mim, lure, luim, piv);
  // k6) k_efuns = modes^{-1} x^T; xint = last column
  lusolve_kernel<<<512, 64, 0, stream>>>(lure, luim, piv, x, out, o_kefuns, cplx,
                                         xint, lim);
  // k7) y_pred scan
  ypred_kernel<<<128, 64, 0, stream>>>(klog, xint, mre, mim, out, o_yadvr, o_yadvi,
                                       yadv, lim);
  // k8) x_adv = decoder(y_adv_real)
  dec4_kernel<<<64, 256, 0, stream>>>(yadv, 512,
      dw0, db0, dw1, db1, dw2, db2, dw3, db3, out + o_xadv, lim);
}

// Round 11
// 5087.729 us; speedup vs baseline: 1.0696x; 1.0696x over previous
//
#include <hip/hip_runtime.h>
#include <hip/hip_bf16.h>

// Problem dims
#define NB 128   // batch
#define NT 256   // time
#define ND 64    // input dim
#define NL 64    // latent dim
#define NH 256   // hidden
#define NP 4     // scan steps

// 30 MiB static device workspace
__device__ double g_ws[3932160];

static __device__ __forceinline__ double dlapy2_(double x, double y) {
  double ax = fabs(x), ay = fabs(y);
  double w = ax > ay ? ax : ay;
  double z = ax > ay ? ay : ax;
  if (z == 0.0) return w;
  double r = z / w;
  return w * sqrt(1.0 + r * r);
}
static __device__ __forceinline__ double sgn1_(double x) { return copysign(1.0, x); }
static __device__ __forceinline__ void cdiv_(double ar, double ai, double br, double bi,
                                             double& cr, double& ci) {
  if (fabs(br) >= fabs(bi)) {
    double r = bi / br, den = br + r * bi;
    cr = (ar + ai * r) / den;
    ci = (ai - ar * r) / den;
  } else {
    double r = br / bi, den = bi + r * br;
    cr = (ar * r + ai) / den;
    ci = (ai * r - ar) / den;
  }
}
static __device__ __forceinline__ void fwg(float* out, long long ofs, long long lim,
                                           double v) {
  if (ofs >= 0 && ofs < lim) out[ofs] = (float)v;
}
// fast fp64 reciprocal: fp32 rcp seed + 2 Newton steps (~1 ulp). Guarded.
static __device__ __forceinline__ double frcp_(double d) {
  float df = (float)d;
  if (df == 0.0f || !isfinite(df)) return 1.0 / d;
  double r = (double)(1.0f / df);
  r = r * (2.0 - d * r);
  r = r * (2.0 - d * r);
  return r;
}
// wave-64 reductions (all lanes get the result)
static __device__ __forceinline__ double wsum_(double v) {
  for (int o = 32; o > 0; o >>= 1) v += __shfl_xor(v, o, 64);
  return v;
}
static __device__ __forceinline__ double wmax_(double v) {
  for (int o = 32; o > 0; o >>= 1) v = fmax(v, __shfl_xor(v, o, 64));
  return v;
}
// Single-wave "barrier": DS ops from one wave are processed in order by the LDS
// unit, so cross-lane LDS communication inside a 64-thread block needs only a
// compiler reordering fence. Zero instructions. (Validated R7-R10.)
static __device__ __forceinline__ void wbar() {
  asm volatile("" ::: "memory");
  __builtin_amdgcn_wave_barrier();
  asm volatile("" ::: "memory");
}

// LAPACK dlanv2: standardize a real 2x2 Schur block
static __device__ void dlanv2_(double& a, double& b, double& c, double& d,
                               double& rt1r, double& rt1i, double& rt2r, double& rt2i,
                               double& cs, double& sn) {
  const double eps = 2.2204460492503131e-16;
  if (c == 0.0) {
    cs = 1.0; sn = 0.0;
  } else if (b == 0.0) {
    cs = 0.0; sn = 1.0;
    double temp = d; d = a; a = temp;
    b = -c; c = 0.0;
  } else if ((a - d) == 0.0 && sgn1_(b) != sgn1_(c)) {
    cs = 1.0; sn = 0.0;
  } else {
    double temp = a - d;
    double p = 0.5 * temp;
    double bcmax = fmax(fabs(b), fabs(c));
    double bcmis = fmin(fabs(b), fabs(c)) * sgn1_(b) * sgn1_(c);
    double scale = fmax(fabs(p), bcmax);
    double z = (p / scale) * p + (bcmax / scale) * bcmis;
    if (z >= 4.0 * eps) {
      z = p + copysign(sqrt(scale) * sqrt(z), p);
      a = d + z;
      d = d - (bcmax / z) * bcmis;
      double tau = dlapy2_(c, z);
      cs = z / tau; sn = c / tau;
      b = b - c; c = 0.0;
    } else {
      double sigma = b + c;
      double tau = dlapy2_(sigma, temp);
      cs = sqrt(0.5 * (1.0 + fabs(sigma) / tau));
      sn = -(p / (tau * cs)) * sgn1_(sigma);
      double aa = a * cs + b * sn, bb = -a * sn + b * cs;
      double cc = c * cs + d * sn, dd = -c * sn + d * cs;
      a = aa * cs + cc * sn; b = bb * cs + dd * sn;
      c = -aa * sn + cc * cs; d = -bb * sn + dd * cs;
      temp = 0.5 * (a + d);
      a = temp; d = temp;
      if (c != 0.0) {
        if (b != 0.0) {
          if (sgn1_(b) == sgn1_(c)) {
            double sab = sqrt(fabs(b)), sac = sqrt(fabs(c));
            double p2 = copysign(sab * sac, c);
            double tau2 = 1.0 / sqrt(fabs(b + c));
            a = temp + p2; d = temp - p2;
            b = b - c; c = 0.0;
            double cs1 = sab * tau2, sn1 = sac * tau2;
            double t0 = cs * cs1 - sn * sn1;
            sn = cs * sn1 + sn * cs1;
            cs = t0;
          }
        } else {
          b = -c; c = 0.0;
          double t0 = cs; cs = -sn; sn = t0;
        }
      }
    }
  }
  rt1r = a; rt2r = d;
  if (c == 0.0) { rt1i = 0.0; rt2i = 0.0; }
  else { rt1i = sqrt(fabs(b)) * sqrt(fabs(c)); rt2i = -rt1i; }
}

// ---------------- encoder only: x -> y (f32 out + f64 ws), fp64 math
__global__ __launch_bounds__(256) void enc_kernel(
    const float* __restrict__ x,
    const float* __restrict__ EW0, const float* __restrict__ EB0,
    const float* __restrict__ EW1, const float* __restrict__ EB1,
    const float* __restrict__ EW2, const float* __restrict__ EB2,
    const float* __restrict__ EW3, const float* __restrict__ EB3,
    float* __restrict__ out_y, double* __restrict__ y64, long long lim)
{
  const int tid = threadIdx.x;
  const long long tok0 = (long long)blockIdx.x * 8;
  __shared__ double xin[8][64];
  __shared__ double h0[8][256];
  __shared__ double h1[8][256];
  for (int idx = tid; idx < 512; idx += 256) {
    int tk = idx >> 6, f2 = idx & 63;
    xin[tk][f2] = (double)x[(tok0 + tk) * 64 + f2];
  }
  __syncthreads();
  { // L1 64->256
    int j = tid; double acc[8]; double bj = (double)EB0[j];
    for (int tk = 0; tk < 8; ++tk) acc[tk] = bj;
#pragma unroll 8
    for (int i2 = 0; i2 < 64; ++i2) {
      double w = (double)EW0[i2 * 256 + j];
      for (int tk = 0; tk < 8; ++tk) acc[tk] += xin[tk][i2] * w;
    }
    for (int tk = 0; tk < 8; ++tk) h0[tk][j] = fmax(acc[tk], 0.0);
  }
  __syncthreads();
  { // L2
    int j = tid; double acc[8]; double bj = (double)EB1[j];
    for (int tk = 0; tk < 8; ++tk) acc[tk] = bj;
#pragma unroll 4
    for (int i2 = 0; i2 < 256; ++i2) {
      double w = (double)EW1[i2 * 256 + j];
      for (int tk = 0; tk < 8; ++tk) acc[tk] += h0[tk][i2] * w;
    }
    for (int tk = 0; tk < 8; ++tk) h1[tk][j] = fmax(acc[tk], 0.0);
  }
  __syncthreads();
  { // L3
    int j = tid; double acc[8]; double bj = (double)EB2[j];
    for (int tk = 0; tk < 8; ++tk) acc[tk] = bj;
#pragma unroll 4
    for (int i2 = 0; i2 < 256; ++i2) {
      double w = (double)EW2[i2 * 256 + j];
      for (int tk = 0; tk < 8; ++tk) acc[tk] += h1[tk][i2] * w;
    }
    for (int tk = 0; tk < 8; ++tk) h0[tk][j] = fmax(acc[tk], 0.0);
  }
  __syncthreads();
  { // L4 256->64 (no relu): y
    int j = tid & 63;
    int tg = tid >> 6;
    double acc0 = (double)EB3[j], acc1 = acc0;
#pragma unroll 4
    for (int i2 = 0; i2 < 256; ++i2) {
      double w = (double)EW3[i2 * 64 + j];
      acc0 += h0[tg * 2][i2] * w;
      acc1 += h0[tg * 2 + 1][i2] * w;
    }
    for (int u = 0; u < 2; ++u) {
      int tk = tg * 2 + u;
      double a = (u == 0) ? acc0 : acc1;
      long long gl = (tok0 + tk) * 64 + j;
      fwg(out_y, gl, lim, a);
      y64[gl] = a;
    }
  }
}

// ---------------- standalone 4-layer decoder on f64 input (for x_adv), fp64
__global__ __launch_bounds__(256) void dec4_kernel(
    const double* __restrict__ inp, long long ntok,
    const float* __restrict__ W0, const float* __restrict__ B0,
    const float* __restrict__ W1, const float* __restrict__ B1,
    const float* __restrict__ W2, const float* __restrict__ B2,
    const float* __restrict__ W3, const float* __restrict__ B3,
    float* __restrict__ outb, long long lim)
{
  const int tid = threadIdx.x;
  const long long tok0 = (long long)blockIdx.x * 8;
  __shared__ double xin[8][64];
  __shared__ double h0[8][256];
  __shared__ double h1[8][256];
  for (int idx = tid; idx < 512; idx += 256) {
    int tk = idx >> 6, f2 = idx & 63;
    long long gl = (tok0 + tk) * 64 + f2;
    xin[tk][f2] = (tok0 + tk < ntok) ? inp[gl] : 0.0;
  }
  __syncthreads();
  {
    int j = tid; double acc[8]; double bj = (double)B0[j];
    for (int tk = 0; tk < 8; ++tk) acc[tk] = bj;
#pragma unroll 8
    for (int i2 = 0; i2 < 64; ++i2) {
      double w = (double)W0[i2 * 256 + j];
      for (int tk = 0; tk < 8; ++tk) acc[tk] += xin[tk][i2] * w;
    }
    for (int tk = 0; tk < 8; ++tk) h0[tk][j] = fmax(acc[tk], 0.0);
  }
  __syncthreads();
  {
    int j = tid; double acc[8]; double bj = (double)B1[j];
    for (int tk = 0; tk < 8; ++tk) acc[tk] = bj;
#pragma unroll 4
    for (int i2 = 0; i2 < 256; ++i2) {
      double w = (double)W1[i2 * 256 + j];
      for (int tk = 0; tk < 8; ++tk) acc[tk] += h0[tk][i2] * w;
    }
    for (int tk = 0; tk < 8; ++tk) h1[tk][j] = fmax(acc[tk], 0.0);
  }
  __syncthreads();
  {
    int j = tid; double acc[8]; double bj = (double)B2[j];
    for (int tk = 0; tk < 8; ++tk) acc[tk] = bj;
#pragma unroll 4
    for (int i2 = 0; i2 < 256; ++i2) {
      double w = (double)W2[i2 * 256 + j];
      for (int tk = 0; tk < 8; ++tk) acc[tk] += h1[tk][i2] * w;
    }
    for (int tk = 0; tk < 8; ++tk) h0[tk][j] = fmax(acc[tk], 0.0);
  }
  __syncthreads();
  {
    int j = tid & 63;
    int tg = tid >> 6;
    double acc0 = (double)B3[j], acc1 = acc0;
#pragma unroll 4
    for (int i2 = 0; i2 < 256; ++i2) {
      double w = (double)W3[i2 * 64 + j];
      acc0 += h0[tg * 2][i2] * w;
      acc1 += h0[tg * 2 + 1][i2] * w;
    }
    for (int u = 0; u < 2; ++u) {
      long long tok = tok0 + tg * 2 + u;
      if (tok < ntok) fwg(outb, tok * 64 + j, lim, (u == 0) ? acc0 : acc1);
    }
  }
}

// ---------------- G = y_m y_m^T, A = y_p y_m^T (per batch), fp64
__global__ __launch_bounds__(256) void buildGA_kernel(const double* __restrict__ y64,
                                                      double* __restrict__ G,
                                                      double* __restrict__ A)
{
  int b = blockIdx.x, tid = threadIdx.x;
  __shared__ double ybuf[65][64];
  const double* yb = y64 + (size_t)b * NT * 64;
  double g[16], a[16];
  for (int s = 0; s < 16; ++s) { g[s] = 0.0; a[s] = 0.0; }
  for (int c0 = 0; c0 < 255; c0 += 64) {
    int nrow = (256 - c0 < 65) ? (256 - c0) : 65;
    for (int idx = tid; idx < nrow * 64; idx += 256) {
      int rr = idx >> 6, f2 = idx & 63;
      ybuf[rr][f2] = yb[(size_t)(c0 + rr) * 64 + f2];
    }
    __syncthreads();
    int tmax = (254 - c0 < 63) ? (254 - c0) : 63;
    for (int s = 0; s < 16; ++s) {
      int id = s * 256 + tid;
      int i2 = id >> 6, j2 = id & 63;
      double gg = g[s], aa = a[s];
      for (int tt = 0; tt <= tmax; ++tt) {
        double yj = ybuf[tt][j2];
        gg += ybuf[tt][i2] * yj;
        aa += ybuf[tt + 1][i2] * yj;
      }
      g[s] = gg; a[s] = aa;
    }
    __syncthreads();
  }
  for (int s = 0; s < 16; ++s) {
    int id = s * 256 + tid;
    G[(size_t)b * 4096 + id] = g[s];
    A[(size_t)b * 4096 + id] = a[s];
  }
}

// ---------------- K = A G^{-1} via Cholesky (G SPD), per batch (single wave)
__global__ __launch_bounds__(64) void cholsolve_kernel(const double* __restrict__ G,
                                                       const double* __restrict__ A,
                                                       double* __restrict__ Km)
{
  int b = blockIdx.x, t = threadIdx.x;
  __shared__ double C[64][65];
  __shared__ double X[64][65];
  const double* Gb = G + (size_t)b * 4096;
  const double* Ab = A + (size_t)b * 4096;
  for (int r = 0; r < 64; ++r) C[r][t] = Gb[r * 64 + t];
  for (int i2 = 0; i2 < 64; ++i2) X[i2][t] = Ab[t * 64 + i2];
  __syncthreads();
  for (int k = 0; k < 64; ++k) {
    double s = C[k][k];
    for (int m2 = 0; m2 < k; ++m2) s -= C[k][m2] * C[k][m2];
    double ckk = sqrt(fmax(s, 1e-300));
    wbar();
    if (t == k) C[k][k] = ckk;
    if (t > k) {
      double v = C[t][k];
      for (int m2 = 0; m2 < k; ++m2) v -= C[t][m2] * C[k][m2];
      C[t][k] = v / ckk;
    }
    wbar();
  }
  for (int i2 = 0; i2 < 64; ++i2) {
    double v = X[i2][t];
    for (int m2 = 0; m2 < i2; ++m2) v -= C[i2][m2] * X[m2][t];
    X[i2][t] = v / C[i2][i2];
  }
  for (int i2 = 63; i2 >= 0; --i2) {
    double v = X[i2][t];
    for (int m2 = i2 + 1; m2 < 64; ++m2) v -= C[m2][i2] * X[m2][t];
    X[i2][t] = v / C[i2][i2];
  }
  wbar();
  for (int i2 = 0; i2 < 64; ++i2)
    Km[(size_t)b * 4096 + (size_t)t * 64 + i2] = X[i2][t];
}

// ---------------- FAT kernel: blocks <128 -> eig; blocks >=128 -> fp32 x_ae decoder
__global__ __launch_bounds__(64) void eig_dec_kernel(
    const double* __restrict__ Kmat,
    double* __restrict__ modes_re, double* __restrict__ modes_im,
    double* __restrict__ klog,
    float* __restrict__ out, long long o_kevals, long long o_kmodes,
    int cplx, long long lim,
    const double* __restrict__ y64,
    const float* __restrict__ DW0, const float* __restrict__ DB0,
    const float* __restrict__ DW1, const float* __restrict__ DB1,
    const float* __restrict__ DW2, const float* __restrict__ DB2,
    const float* __restrict__ DW3, const float* __restrict__ DB3,
    float* __restrict__ out_xae)
{
  const int t = threadIdx.x;
  __shared__ __align__(16) double smem[8704];   // 69632 B, shared by both paths

  if (blockIdx.x >= NB) {
    // ---------- fp32 decoder for x_ae, 8 tokens per block ----------
    const int blk = blockIdx.x - NB;
    const long long tok0 = (long long)blk * 8;
    float (*fx)[64] = (float (*)[64])(smem);
    float (*fh0)[256] = (float (*)[256])(smem + 256);
    float (*fh1)[256] = (float (*)[256])(smem + 1280);
    for (int idx = t; idx < 512; idx += 64) {
      int tk = idx >> 6, f2 = idx & 63;
      fx[tk][f2] = (float)y64[(tok0 + tk) * 64 + f2];
    }
    __syncthreads();
    float acc[4][8];
    for (int s = 0; s < 4; ++s) {
      float bj = DB0[t + 64 * s];
      for (int tk = 0; tk < 8; ++tk) acc[s][tk] = bj;
    }
#pragma unroll 4
    for (int i = 0; i < 64; ++i) {
      float xv[8];
      for (int tk = 0; tk < 8; ++tk) xv[tk] = fx[tk][i];
      for (int s = 0; s < 4; ++s) {
        float w = DW0[i * 256 + t + 64 * s];
        for (int tk = 0; tk < 8; ++tk) acc[s][tk] += xv[tk] * w;
      }
    }
    for (int s = 0; s < 4; ++s)
      for (int tk = 0; tk < 8; ++tk) fh0[tk][t + 64 * s] = fmaxf(acc[s][tk], 0.0f);
    __syncthreads();
    for (int s = 0; s < 4; ++s) {
      float bj = DB1[t + 64 * s];
      for (int tk = 0; tk < 8; ++tk) acc[s][tk] = bj;
    }
#pragma unroll 2
    for (int i = 0; i < 256; ++i) {
      float xv[8];
      for (int tk = 0; tk < 8; ++tk) xv[tk] = fh0[tk][i];
      for (int s = 0; s < 4; ++s) {
        float w = DW1[i * 256 + t + 64 * s];
        for (int tk = 0; tk < 8; ++tk) acc[s][tk] += xv[tk] * w;
      }
    }
    for (int s = 0; s < 4; ++s)
      for (int tk = 0; tk < 8; ++tk) fh1[tk][t + 64 * s] = fmaxf(acc[s][tk], 0.0f);
    __syncthreads();
    for (int s = 0; s < 4; ++s) {
      float bj = DB2[t + 64 * s];
      for (int tk = 0; tk < 8; ++tk) acc[s][tk] = bj;
    }
#pragma unroll 2
    for (int i = 0; i < 256; ++i) {
      float xv[8];
      for (int tk = 0; tk < 8; ++tk) xv[tk] = fh1[tk][i];
      for (int s = 0; s < 4; ++s) {
        float w = DW2[i * 256 + t + 64 * s];
        for (int tk = 0; tk < 8; ++tk) acc[s][tk] += xv[tk] * w;
      }
    }
    for (int s = 0; s < 4; ++s)
      for (int tk = 0; tk < 8; ++tk) fh0[tk][t + 64 * s] = fmaxf(acc[s][tk], 0.0f);
    __syncthreads();
    float a4[8];
    float bj3 = DB3[t];
    for (int tk = 0; tk < 8; ++tk) a4[tk] = bj3;
#pragma unroll 2
    for (int i = 0; i < 256; ++i) {
      float w = DW3[i * 64 + t];
      for (int tk = 0; tk < 8; ++tk) a4[tk] += fh0[tk][i] * w;
    }
    for (int tk = 0; tk < 8; ++tk)
      fwg(out_xae, (tok0 + tk) * 64 + t, lim, (double)a4[tk]);
    return;
  }

  // ---------- eig path (blocks 0..127, single wave) ----------
  const int b = blockIdx.x;
  double (*Hs)[65] = (double (*)[65])smem;           // 4160 doubles
  double (*Zs)[65] = (double (*)[65])(smem + 4160);  // 4160 doubles, Zs[col][row]
  double* wr = smem + 8320;
  double* wi = wr + 64;
  double* bscale = wi + 64;
  double* tau = bscale + 64;
  double* xr = tau + 64;
  double* xi = xr + 64;
  double* mre = modes_re + (size_t)b * 4096;  // row-major [row*64+col]
  double* mim = modes_im + (size_t)b * 4096;

  const double ulp = 2.2204460492503131e-16;
  const double safmin = 2.2250738585072014e-308;

  for (int r = 0; r < 64; ++r) Hs[r][t] = Kmat[(size_t)b * 4096 + r * 64 + t];
  bscale[t] = 1.0;
  __syncthreads();

  // ---- dgebal scaling
  {
    const double sclfac = 2.0, factor = 0.95;
    const double sfmin1 = safmin / ulp;
    const double sfmax1 = 1.0 / sfmin1;
    const double sfmin2 = sfmin1 * sclfac;
    const double sfmax2 = 1.0 / sfmin2;
    for (int sweep = 0; sweep < 64; ++sweep) {
      bool noconv = false;
      for (int i = 0; i < 64; ++i) {
        double colv = fabs(Hs[t][i]);
        double rowv = fabs(Hs[i][t]);
        double c = wsum_((t == i) ? 0.0 : colv);
        double r = wsum_((t == i) ? 0.0 : rowv);
        double ca = wmax_(colv);
        double ra = wmax_(rowv);
        if (c == 0.0 || r == 0.0) continue;
        double g = r / sclfac, f = 1.0, s = c + r;
        while (c < g) {
          if (fmax(fmax(f, c), ca) >= sfmax2 || fmin(fmin(r, g), ra) <= sfmin2) break;
          f *= sclfac; c *= sclfac; ca *= sclfac;
          r /= sclfac; g /= sclfac; ra /= sclfac;
        }
        g = c / sclfac;
        while (g >= r) {
          if (fmax(r, ra) >= sfmax2 || fmin(fmin(fmin(f, c), g), ca) <= sfmin2) break;
          f /= sclfac; c /= sclfac; g /= sclfac; ca /= sclfac;
          r *= sclfac; ra *= sclfac;
        }
        if (c + r >= factor * s) continue;
        double bsi = bscale[i];
        if (f < 1.0 && bsi < 1.0) { if (f * bsi <= sfmin1) continue; }
        if (f > 1.0 && bsi > 1.0) { if (bsi >= sfmax1 / f) continue; }
        double gi = 1.0 / f;
        Hs[i][t] *= gi;
        Hs[t][i] *= f;
        if (t == 0) bscale[i] = bsi * f;
        noconv = true;
        wbar();
      }
      if (!noconv) break;
    }
    wbar();
  }

  // ---- dgehd2
  for (int i = 0; i < 62; ++i) {
    double alpha = Hs[i + 1][i];
    double contrib = (t >= i + 2) ? Hs[t][i] * Hs[t][i] : 0.0;
    double ss = wsum_(contrib);
    double taui, beta;
    if (ss == 0.0) {
      taui = 0.0; beta = alpha;
    } else {
      beta = -copysign(sqrt(alpha * alpha + ss), alpha);
      taui = (beta - alpha) / beta;
      double sc = 1.0 / (alpha - beta);
      if (t >= i + 2) Hs[t][i] *= sc;
    }
    if (t == 0) { tau[i] = taui; Hs[i + 1][i] = beta; }
    wbar();
    if (taui != 0.0) {
      {
        double sum = Hs[t][i + 1];
        for (int k = i + 2; k < 64; ++k) sum += Hs[t][k] * Hs[k][i];
        sum *= taui;
        Hs[t][i + 1] -= sum;
        for (int k = i + 2; k < 64; ++k) Hs[t][k] -= sum * Hs[k][i];
      }
      wbar();
      if (t >= i + 1) {
        double sum = Hs[i + 1][t];
        for (int k = i + 2; k < 64; ++k) sum += Hs[k][i] * Hs[k][t];
        sum *= taui;
        Hs[i + 1][t] -= sum;
        for (int k = i + 2; k < 64; ++k) Hs[k][t] -= sum * Hs[k][i];
      }
      wbar();
    }
  }

  // ---- dorghr: Zs[col][row], lane t owns column t
  {
    for (int r = 0; r < 64; ++r) Zs[t][r] = (r == t) ? 1.0 : 0.0;
    for (int i = 61; i >= 0; --i) {
      double taui = tau[i];
      if (taui != 0.0) {
        double sum = Zs[t][i + 1];
        for (int k = i + 2; k < 64; ++k) sum += Hs[k][i] * Zs[t][k];
        sum *= taui;
        Zs[t][i + 1] -= sum;
        for (int k = i + 2; k < 64; ++k) Zs[t][k] -= sum * Hs[k][i];
      }
    }
  }
  wbar();
  for (int r = t + 2; r < 64; ++r) Hs[r][t] = 0.0;
  __syncthreads();

  // ---- dlahqr (wantt, wantz)
  {
    const int lo = 0, hi = 63;
    const double dat1 = 0.75, dat2 = -0.4375;
    const int kexsh = 10;
    const double smlnum = safmin * (64.0 / ulp);
    int I = hi;
    int kdefl = 0;
    while (I >= lo) {
      int L = lo;
      bool done = false;
      const int itmax = 30 * 64;
      for (int its = 0; its <= itmax; ++its) {
        int k;
        {
          bool pred = false;
          int kl = t;
          if (kl > L && kl <= I) {
            double sub = fabs(Hs[kl][kl - 1]);
            if (sub <= smlnum) pred = true;
            else {
              double tst = fabs(Hs[kl - 1][kl - 1]) + fabs(Hs[kl][kl]);
              if (tst == 0.0) {
                if (kl - 2 >= lo) tst += fabs(Hs[kl - 1][kl - 2]);
                if (kl + 1 <= hi) tst += fabs(Hs[kl + 1][kl]);
              }
              if (sub <= ulp * tst) {
                double h12a = fabs(Hs[kl - 1][kl]);
                double ab = fmax(sub, h12a), ba = fmin(sub, h12a);
                double hkk = fabs(Hs[kl][kl]);
                double dif = fabs(Hs[kl - 1][kl - 1] - Hs[kl][kl]);
                double aa = fmax(hkk, dif), bb2 = fmin(hkk, dif);
                double s = aa + ab;
                if (ba * (ab / s) <= fmax(smlnum, ulp * (bb2 * (aa / s)))) pred = true;
              }
            }
          }
          unsigned long long msk = __ballot(pred);
          k = msk ? (63 - __builtin_clzll(msk)) : L;
        }
        L = k;
        if (L > lo) { if (t == 0) Hs[L][L - 1] = 0.0; }
        wbar();
        if (L >= I - 1) { done = true; break; }
        kdefl++;
        double h11, h12, h21, h22;
        if (kdefl % (2 * kexsh) == 0) {
          double s = dat1 * (fabs(Hs[I][I - 1]) + fabs(Hs[I - 1][I - 2]));
          h11 = dat2 * s + Hs[I][I]; h12 = s; h21 = s; h22 = h11;
        } else if (kdefl % kexsh == 0) {
          double s = dat1 * (fabs(Hs[L + 1][L]) + fabs(Hs[L + 2][L + 1]));
          h11 = dat2 * s + Hs[L][L]; h12 = s; h21 = s; h22 = h11;
        } else {
          h11 = Hs[I - 1][I - 1]; h21 = Hs[I][I - 1];
          h12 = Hs[I - 1][I];     h22 = Hs[I][I];
        }
        double rt1r, rt1i, rt2r, rt2i;
        {
          double s = fabs(h11) + fabs(h12) + fabs(h21) + fabs(h22);
          if (s == 0.0) { rt1r = rt1i = rt2r = rt2i = 0.0; }
          else {
            double a_ = h11 / s, c_ = h21 / s, b_ = h12 / s, d_ = h22 / s;
            double tr = a_ + d_;
            double det = (a_ - d_) * (a_ - d_) * 0.25 + b_ * c_;
            if (det >= 0.0) {
              double rtdisc = sqrt(det);
              double r1 = tr * 0.5 + rtdisc;
              double r2 = tr * 0.5 - rtdisc;
              double pick = (fabs(r1 - d_) <= fabs(r2 - d_)) ? r1 : r2;
              rt1r = pick * s; rt2r = rt1r; rt1i = 0.0; rt2i = 0.0;
            } else {
              rt1r = tr * 0.5 * s; rt2r = rt1r;
              rt1i = sqrt(-det) * s; rt2i = -rt1i;
            }
          }
        }
        int m; double v0, v1, v2;
        {
          double w0 = 0.0, w1 = 0.0, w2 = 0.0;
          bool ok = false;
          int mm = t;
          if (mm >= L && mm <= I - 2) {
            double h21s = Hs[mm + 1][mm];
            double s = fabs(Hs[mm][mm] - rt2r) + fabs(rt2i) + fabs(h21s);
            h21s = Hs[mm + 1][mm] / s;
            w0 = h21s * Hs[mm][mm + 1] + (Hs[mm][mm] - rt1r) * ((Hs[mm][mm] - rt2r) / s)
                 - rt1i * (rt2i / s);
            w1 = h21s * (Hs[mm][mm] + Hs[mm + 1][mm + 1] - rt1r - rt2r);
            w2 = h21s * Hs[mm + 2][mm + 1];
            double s2 = fabs(w0) + fabs(w1) + fabs(w2);
            w0 /= s2; w1 /= s2; w2 /= s2;
            if (mm == L) ok = true;
            else ok = (fabs(Hs[mm][mm - 1]) * (fabs(w1) + fabs(w2)) <=
                       ulp * fabs(w0) *
                           (fabs(Hs[mm - 1][mm - 1]) + fabs(Hs[mm][mm]) +
                            fabs(Hs[mm + 1][mm + 1])));
          }
          unsigned long long msk = __ballot(ok);
          m = 63 - __builtin_clzll(msk);
          v0 = __shfl(w0, m); v1 = __shfl(w1, m); v2 = __shfl(w2, m);
        }
        // ---- bulge chase (R9 structure: row preloads + Z register carry;
        // fast reciprocals in dlarfg are the only delta vs R9)
        double c0 = 0.0, c1 = 0.0, c2 = 0.0;
        double zc0 = 0.0, zc1 = 0.0;
        for (int kk = m; kk <= I - 1; ++kk) {
          int nr = (3 < I - kk + 1) ? 3 : (I - kk + 1);
          // row preloads: phase A is the first toucher of rows kk..kk+2 this
          // step, so these reads are off the intra-step dependency chain and
          // their latency hides under dlarfg.
          double a0 = Hs[kk][t];
          double a1 = Hs[kk + 1][t];
          double a2 = (nr == 3) ? Hs[kk + 2][t] : 0.0;
          // Z: rows kk,kk+1 were written by THIS lane last step -> register carry
          double z0, z1;
          if (kk > m) { z0 = zc0; z1 = zc1; }
          else { z0 = Zs[kk][t]; z1 = Zs[kk + 1][t]; }
          double z2 = (nr == 3) ? Zs[kk + 2][t] : 0.0;
          double u0, u1, u2 = 0.0;
          if (kk > m) { u0 = c0; u1 = c1; u2 = (nr == 3) ? c2 : 0.0; }
          else        { u0 = v0; u1 = v1; u2 = (nr == 3) ? v2 : 0.0; }
          double t1;
          {  // dlarfg, plain sqrt + fast reciprocals
            double xn2 = u1 * u1 + u2 * u2;
            if (xn2 == 0.0) t1 = 0.0;
            else {
              double beta = -copysign(sqrt(u0 * u0 + xn2), u0);
              t1 = (beta - u0) * frcp_(beta);
              double sc = frcp_(u0 - beta);
              u1 *= sc; u2 *= sc;
              u0 = beta;
            }
          }
          double t2 = t1 * u1, t3 = t1 * u2;
          // phase A: left(row) update from preloaded values + reflector storage
          if (t >= kk) {
            double sum = a0 + u1 * a1 + u2 * a2;
            Hs[kk][t] = a0 - sum * t1;
            Hs[kk + 1][t] = a1 - sum * t2;
            if (nr == 3) Hs[kk + 2][t] = a2 - sum * t3;
          }
          if (t == 0) {
            if (kk > m) {
              Hs[kk][kk - 1] = u0;
              Hs[kk + 1][kk - 1] = 0.0;
              if (kk < I - 1) Hs[kk + 2][kk - 1] = 0.0;
            } else if (m > L) {
              Hs[kk][kk - 1] *= (1.0 - t1);
            }
          }
          wbar();
          // phase B: right(col) update (reads after fence) + Z from regs
          int rmax = (kk + 3 < I) ? kk + 3 : I;
          double nv0 = 0.0;
          if (t <= rmax) {
            double b0 = Hs[t][kk], b1 = Hs[t][kk + 1];
            double b2 = (nr == 3) ? Hs[t][kk + 2] : 0.0;
            double sB = b0 + u1 * b1 + u2 * b2;
            nv0 = b0 - sB * t1;
            Hs[t][kk] = nv0;
            Hs[t][kk + 1] = b1 - sB * t2;
            if (nr == 3) Hs[t][kk + 2] = b2 - sB * t3;
          }
          {
            double sZ = z0 + u1 * z1 + u2 * z2;
            Zs[kk][t] = z0 - sZ * t1;
            zc0 = z1 - sZ * t2;
            Zs[kk + 1][t] = zc0;
            if (nr == 3) {
              zc1 = z2 - sZ * t3;
              Zs[kk + 2][t] = zc1;
            }
          }
          int s1 = (kk + 1 < 64) ? kk + 1 : 63;
          int s2 = (kk + 2 < 64) ? kk + 2 : 63;
          int s3 = (kk + 3 < 64) ? kk + 3 : 63;
          c0 = __shfl(nv0, s1, 64);
          c1 = __shfl(nv0, s2, 64);
          c2 = __shfl(nv0, s3, 64);
          wbar();
        }
      } // its
      if (!done) {  // failsafe
        wbar();
        if (t == 0) {
          for (int r = lo; r <= I; ++r) { wr[r] = Hs[r][r]; wi[r] = 0.0; }
        }
        wbar();
        I = lo - 1;
        kdefl = 0;
        continue;
      }
      if (L == I) {
        if (t == 0) { wr[I] = Hs[I][I]; wi[I] = 0.0; }
        wbar();
      } else {  // 2x2 block: dlanv2 + rotations
        double a_ = Hs[I - 1][I - 1], b_ = Hs[I - 1][I];
        double c_ = Hs[I][I - 1],     d_ = Hs[I][I];
        double r1r, r1i, r2r, r2i, cs, sn;
        dlanv2_(a_, b_, c_, d_, r1r, r1i, r2r, r2i, cs, sn);
        wbar();
        if (t == 0) {
          Hs[I - 1][I - 1] = a_; Hs[I - 1][I] = b_;
          Hs[I][I - 1] = c_;     Hs[I][I] = d_;
          wr[I - 1] = r1r; wi[I - 1] = r1i;
          wr[I] = r2r;     wi[I] = r2i;
        }
        wbar();
        if (t > I) {
          double x = Hs[I - 1][t], y = Hs[I][t];
          Hs[I - 1][t] = cs * x + sn * y;
          Hs[I][t] = cs * y - sn * x;
        }
        if (t < I - 1) {
          double x = Hs[t][I - 1], y = Hs[t][I];
          Hs[t][I - 1] = cs * x + sn * y;
          Hs[t][I] = cs * y - sn * x;
        }
        {
          double x = Zs[I - 1][t], y = Zs[I][t];
          Zs[I - 1][t] = cs * x + sn * y;
          Zs[I][t] = cs * y - sn * x;
        }
        wbar();
      }
      kdefl = 0;
      I = L - 1;
    }
  }
  __syncthreads();

  // ---- dtrevc + dgebak + normalization
  const double smln = safmin * (64.0 / ulp);
  int ki = 63;
  while (ki >= 0) {
    wbar();
    bool pair = (ki > 0) && (Hs[ki][ki - 1] != 0.0);
    if (!pair) {
      double lam = wr[ki];
      double smin = fmax(ulp * fabs(lam), smln);
      xr[t] = (t < ki) ? -Hs[t][ki] : ((t == ki) ? 1.0 : 0.0);
      wbar();
      int j = ki - 1;
      while (j >= 0) {
        bool blk2 = (j > 0) && (Hs[j][j - 1] != 0.0);
        if (!blk2) {
          double den = Hs[j][j] - lam;
          if (fabs(den) < smin) den = smin;
          double xj = xr[j] / den;
          if (t == j) xr[j] = xj;
          else if (t < j) xr[t] -= xj * Hs[t][j];
          wbar();
          j -= 1;
        } else {
          double t11 = Hs[j - 1][j - 1] - lam, t12 = Hs[j - 1][j];
          double t21 = Hs[j][j - 1], t22 = Hs[j][j] - lam;
          double det = t11 * t22 - t12 * t21;
          if (fabs(det) < smin * smin) det = copysign(smin * smin, (det == 0.0) ? 1.0 : det);
          double b1 = xr[j - 1], b2 = xr[j];
          double x1 = (b1 * t22 - t12 * b2) / det;
          double x2 = (t11 * b2 - t21 * b1) / det;
          if (t == j - 1) xr[j - 1] = x1;
          else if (t == j) xr[j] = x2;
          else if (t < j - 1) xr[t] -= x1 * Hs[t][j - 1] + x2 * Hs[t][j];
          wbar();
          j -= 2;
        }
      }
      double acc = 0.0;
      for (int k2 = 0; k2 <= ki; ++k2) acc += Zs[k2][t] * xr[k2];
      acc *= bscale[t];
      double nn = wsum_(acc * acc);
      double scl = 1.0 / sqrt(nn);
      mre[t * 64 + ki] = acc * scl;
      mim[t * 64 + ki] = 0.0;
      ki -= 1;
    } else {
      double wre = Hs[ki][ki];
      double wim = sqrt(fabs(Hs[ki][ki - 1])) * sqrt(fabs(Hs[ki - 1][ki]));
      double smin = fmax(ulp * (fabs(wre) + wim), smln);
      double seed_r_km1, seed_i_k;
      if (fabs(Hs[ki - 1][ki]) >= fabs(Hs[ki][ki - 1])) {
        seed_r_km1 = 1.0;
        seed_i_k = wim / Hs[ki - 1][ki];
      } else {
        seed_r_km1 = -wim / Hs[ki][ki - 1];
        seed_i_k = 1.0;
      }
      if (t < ki - 1) {
        xr[t] = -seed_r_km1 * Hs[t][ki - 1];
        xi[t] = -seed_i_k * Hs[t][ki];
      } else if (t == ki - 1) { xr[t] = seed_r_km1; xi[t] = 0.0; }
      else if (t == ki) { xr[t] = 0.0; xi[t] = seed_i_k; }
      else { xr[t] = 0.0; xi[t] = 0.0; }
      wbar();
      int j = ki - 2;
      while (j >= 0) {
        bool blk2 = (j > 0) && (Hs[j][j - 1] != 0.0);
        if (!blk2) {
          double dr = Hs[j][j] - wre, di = -wim;
          if (fabs(dr) + fabs(di) < smin) { dr = smin; di = 0.0; }
          double xjr, xji;
          cdiv_(xr[j], xi[j], dr, di, xjr, xji);
          if (t == j) { xr[j] = xjr; xi[j] = xji; }
          else if (t < j) {
            xr[t] -= xjr * Hs[t][j];
            xi[t] -= xji * Hs[t][j];
          }
          wbar();
          j -= 1;
        } else {
          double t11 = Hs[j - 1][j - 1] - wre, t12 = Hs[j - 1][j];
          double t21 = Hs[j][j - 1], t22 = Hs[j][j] - wre;
          double detr = t11 * t22 - wim * wim - t12 * t21;
          double deti = -wim * (t11 + t22);
          double b1r = xr[j - 1], b1i = xi[j - 1];
          double b2r = xr[j], b2i = xi[j];
          double n1r = b1r * t22 + b1i * wim - t12 * b2r;
          double n1i = b1i * t22 - b1r * wim - t12 * b2i;
          double n2r = t11 * b2r + b2i * wim - t21 * b1r;
          double n2i = t11 * b2i - b2r * wim - t21 * b1i;
          double x1r, x1i, x2r, x2i;
          cdiv_(n1r, n1i, detr, deti, x1r, x1i);
          cdiv_(n2r, n2i, detr, deti, x2r, x2i);
          if (t == j - 1) { xr[t] = x1r; xi[t] = x1i; }
          else if (t == j) { xr[t] = x2r; xi[t] = x2i; }
          else if (t < j - 1) {
            xr[t] -= x1r * Hs[t][j - 1] + x2r * Hs[t][j];
            xi[t] -= x1i * Hs[t][j - 1] + x2i * Hs[t][j];
          }
          wbar();
          j -= 2;
        }
      }
      double ar = 0.0, ai = 0.0;
      for (int k2 = 0; k2 <= ki; ++k2) {
        double z = Zs[k2][t];
        ar += z * xr[k2];
        ai += z * xi[k2];
      }
      ar *= bscale[t]; ai *= bscale[t];
      double n2a = wsum_(ar * ar), n2b = wsum_(ai * ai);
      double scl = 1.0 / dlapy2_(sqrt(n2a), sqrt(n2b));
      double vr0 = ar * scl, vi0 = ai * scl;
      double mm = vr0 * vr0 + vi0 * vi0;
      double mmax = wmax_(mm);
      unsigned long long msk = __ballot(mm == mmax);
      int kmx = __ffsll((unsigned long long)msk) - 1;
      double f = __shfl(vr0, kmx), g = __shfl(vi0, kmx);
      double cs_, sn_;
      if (g == 0.0) { cs_ = 1.0; sn_ = 0.0; }
      else if (f == 0.0) { cs_ = 0.0; sn_ = sgn1_(g); }
      else {
        double dd = sqrt(f * f + g * g);
        double sg = sgn1_(f);
        cs_ = fabs(f) / dd;
        sn_ = sg * g / dd;
      }
      double nr0 = cs_ * vr0 + sn_ * vi0;
      double ni0 = cs_ * vi0 - sn_ * vr0;
      if (t == kmx) ni0 = 0.0;
      mre[t * 64 + (ki - 1)] = nr0;
      mim[t * 64 + (ki - 1)] = ni0;
      mre[t * 64 + ki] = nr0;
      mim[t * 64 + ki] = -ni0;
      ki -= 2;
    }
  }

  // ---- k_evals = log(lambda) and outputs
  {
    double er = wr[t], ei = wi[t];
    double lr = log(dlapy2_(er, ei));
    double li = atan2(ei, er);
    klog[(size_t)b * 128 + 2 * t] = lr;
    klog[(size_t)b * 128 + 2 * t + 1] = li;
    if (cplx) {
      fwg(out, o_kevals + ((long long)b * 64 + t) * 2, lim, lr);
      fwg(out, o_kevals + ((long long)b * 64 + t) * 2 + 1, lim, li);
    } else {
      fwg(out, o_kevals + (long long)b * 64 + t, lim, lr);
    }
  }
  for (int k2 = 0; k2 < 64; ++k2) {
    long long idx = ((long long)b * 64 + t) * 64 + k2;
    if (cplx) {
      fwg(out, o_kmodes + idx * 2, lim, mre[t * 64 + k2]);
      fwg(out, o_kmodes + idx * 2 + 1, lim, mim[t * 64 + k2]);
    } else {
      fwg(out, o_kmodes + idx, lim, mre[t * 64 + k2]);
    }
  }
}

// ---------------- complex LU with |re|+|im| partial pivoting (single wave)
__global__ __launch_bounds__(64) void lu_kernel(
    const double* __restrict__ mre, const double* __restrict__ mim,
    double* __restrict__ lure, double* __restrict__ luim, int* __restrict__ piv)
{
  int b = blockIdx.x, t = threadIdx.x;
  __shared__ double Lre[64][65], Lim[64][65];
  for (int r = 0; r < 64; ++r) {
    Lre[r][t] = mre[(size_t)b * 4096 + r * 64 + t];
    Lim[r][t] = mim[(size_t)b * 4096 + r * 64 + t];
  }
  __syncthreads();
  for (int k = 0; k < 64; ++k) {
    double mval = (t >= k) ? (fabs(Lre[t][k]) + fabs(Lim[t][k])) : -1.0;
    double mmax = wmax_(mval);
    unsigned long long msk = __ballot(mval == mmax);
    int p = __ffsll(msk) - 1;
    if (t == 0) piv[b * 64 + k] = p;
    if (p != k) {
      double a0 = Lre[k][t], a1 = Lim[k][t];
      Lre[k][t] = Lre[p][t]; Lim[k][t] = Lim[p][t];
      Lre[p][t] = a0; Lim[p][t] = a1;
    }
    wbar();
    double pr = Lre[k][k], pi = Lim[k][k];
    if (t > k) {
      double lr, li;
      cdiv_(Lre[t][k], Lim[t][k], pr, pi, lr, li);
      Lre[t][k] = lr; Lim[t][k] = li;
      for (int c = k + 1; c < 64; ++c) {
        double ur = Lre[k][c], ui = Lim[k][c];
        Lre[t][c] -= lr * ur - li * ui;
        Lim[t][c] -= lr * ui + li * ur;
      }
    }
    wbar();
  }
  for (int r = 0; r < 64; ++r) {
    lure[(size_t)b * 4096 + r * 64 + t] = Lre[r][t];
    luim[(size_t)b * 4096 + r * 64 + t] = Lim[r][t];
  }
}

// ---------------- solve modes * X = x^T per batch (256 RHS, 4 chunks of 64)
__global__ __launch_bounds__(64) void lusolve_kernel(
    const double* __restrict__ lure, const double* __restrict__ luim,
    const int* __restrict__ piv, const float* __restrict__ x_in,
    float* __restrict__ out, long long o_kefuns, int cplx,
    double* __restrict__ xint, long long lim)
{
  int b = blockIdx.x >> 2;
  int chunk = blockIdx.x & 3;
  int t = threadIdx.x;
  int tglob = chunk * 64 + t;
  __shared__ double br_[64][64], bi_[64][64];
  const double* Lr = lure + (size_t)b * 4096;
  const double* Li = luim + (size_t)b * 4096;
  for (int i2 = 0; i2 < 64; ++i2) {
    br_[i2][t] = (double)x_in[((size_t)b * 256 + tglob) * 64 + i2];
    bi_[i2][t] = 0.0;
  }
  const int* pv = piv + b * 64;
  for (int k = 0; k < 64; ++k) {
    int p = pv[k];
    if (p != k) {
      double a0 = br_[k][t], a1 = bi_[k][t];
      br_[k][t] = br_[p][t]; bi_[k][t] = bi_[p][t];
      br_[p][t] = a0; bi_[p][t] = a1;
    }
  }
  for (int k = 0; k < 63; ++k) {
    double bkr = br_[k][t], bki = bi_[k][t];
    for (int i2 = k + 1; i2 < 64; ++i2) {
      double lr = Lr[i2 * 64 + k], li = Li[i2 * 64 + k];
      br_[i2][t] -= lr * bkr - li * bki;
      bi_[i2][t] -= lr * bki + li * bkr;
    }
  }
  for (int k = 63; k >= 0; --k) {
    double xr0, xi0;
    cdiv_(br_[k][t], bi_[k][t], Lr[k * 64 + k], Li[k * 64 + k], xr0, xi0);
    br_[k][t] = xr0; bi_[k][t] = xi0;
    for (int i2 = 0; i2 < k; ++i2) {
      double ur = Lr[i2 * 64 + k], ui = Li[i2 * 64 + k];
      br_[i2][t] -= ur * xr0 - ui * xi0;
      bi_[i2][t] -= ur * xi0 + ui * xr0;
    }
  }
  for (int i2 = 0; i2 < 64; ++i2) {
    long long idx = ((long long)b * 64 + i2) * 256 + tglob;
    if (cplx) {
      fwg(out, o_kefuns + idx * 2, lim, br_[i2][t]);
      fwg(out, o_kefuns + idx * 2 + 1, lim, bi_[i2][t]);
    } else {
      fwg(out, o_kefuns + idx, lim, br_[i2][t]);
    }
  }
  if (tglob == 255) {
    for (int i2 = 0; i2 < 64; ++i2) {
      xint[(size_t)b * 128 + 2 * i2] = br_[i2][t];
      xint[(size_t)b * 128 + 2 * i2 + 1] = bi_[i2][t];
    }
  }
}

// ---------------- y_pred scan
__global__ __launch_bounds__(64) void ypred_kernel(
    const double* __restrict__ klog, const double* __restrict__ xint,
    const double* __restrict__ mre, const double* __restrict__ mim,
    float* __restrict__ out, long long o_yadvr, long long o_yadvi,
    double* __restrict__ yadv64, long long lim)
{
  int b = blockIdx.x, t = threadIdx.x;
  __shared__ double er[64], ei[64], wxr[64], wxi[64];
  double kr = klog[(size_t)b * 128 + 2 * t], kiv = klog[(size_t)b * 128 + 2 * t + 1];
  er[t] = kr * kr - kiv * kiv;
  ei[t] = 2.0 * kr * kiv;
  double xr0 = xint[(size_t)b * 128 + 2 * t], xi0 = xint[(size_t)b * 128 + 2 * t + 1];
  __syncthreads();
  for (int p = 0; p < 4; ++p) {
    wxr[t] = er[t] * xr0 - ei[t] * xi0;
    wxi[t] = er[t] * xi0 + ei[t] * xr0;
    __syncthreads();
    double ar = 0.0, ai = 0.0;
    const double* mr = mre + (size_t)b * 4096 + (size_t)t * 64;
    const double* mi = mim + (size_t)b * 4096 + (size_t)t * 64;
    for (int k = 0; k < 64; ++k) {
      double wr0 = wxr[k], wi0 = wxi[k];
      ar += mr[k] * wr0 - mi[k] * wi0;
      ai += mr[k] * wi0 + mi[k] * wr0;
    }
    long long idx = ((long long)b * 4 + p) * 64 + t;
    fwg(out, o_yadvr + idx, lim, ar);
    fwg(out, o_yadvi + idx, lim, ai);
    yadv64[idx] = ar;
    double e2r = er[t] * er[t] - ei[t] * ei[t];
    double e2i = 2.0 * er[t] * ei[t];
    __syncthreads();
    er[t] = e2r; ei[t] = e2i;
    __syncthreads();
  }
}

extern "C" void kernel_launch(void* const* d_in, const int* in_sizes, int n_in,
                              void* d_out, int out_size, void* d_ws, size_t ws_size,
                              hipStream_t stream) {
  (void)in_sizes; (void)n_in; (void)d_ws; (void)ws_size;
  const float* x = (const float*)d_in[0];
  const float* ew0 = (const float*)d_in[1];  const float* eb0 = (const float*)d_in[2];
  const float* ew1 = (const float*)d_in[3];  const float* eb1 = (const float*)d_in[4];
  const float* ew2 = (const float*)d_in[5];  const float* eb2 = (const float*)d_in[6];
  const float* ew3 = (const float*)d_in[7];  const float* eb3 = (const float*)d_in[8];
  const float* dw0 = (const float*)d_in[9];  const float* db0 = (const float*)d_in[10];
  const float* dw1 = (const float*)d_in[11]; const float* db1 = (const float*)d_in[12];
  const float* dw2 = (const float*)d_in[13]; const float* db2 = (const float*)d_in[14];
  const float* dw3 = (const float*)d_in[15]; const float* db3 = (const float*)d_in[16];
  float* out = (float*)d_out;   // output dtype is FLOAT32
  const long long lim = (long long)out_size;

  void* wsp = nullptr;
  hipGetSymbolAddress(&wsp, HIP_SYMBOL(g_ws));
  char* ws = (char*)wsp;
  // Alias audit (per-kernel live sets, all disjoint):
  double* y64  = (double*)(ws + 0);            // [0,16M)   k1 -> eig_dec(decoder)
  double* G    = (double*)(ws + 16777216);     // [16,20M)  k2 -> k3
  double* A    = (double*)(ws + 20971520);     // [20,24M)  k2 -> k3
  double* Km   = (double*)(ws + 25165824);     // [24,28M)  k3 -> k4
  double* mre  = (double*)(ws + 16777216);     // [16,20M)  k4 -> k7 (G dead)
  double* mim  = (double*)(ws + 20971520);     // [20,24M)  k4 -> k7 (A dead)
  double* lure = (double*)(ws + 25165824);     // [24,28M)  k5 -> k6 (Km dead)
  double* luim = (double*)(ws + 0);            // [0,4M)    k5 -> k6 (y64 dead)
  double* klog = (double*)(ws + 29360128);     // +128K     k4 -> k7
  double* xint = (double*)(ws + 29491200);     // +128K     k6 -> k7
  double* yadv = (double*)(ws + 29622272);     // +256K     k7 -> k8
  int*    piv  = (int*)   (ws + 29884416);     // +32K      k5 -> k6

  const long long n_y = 2097152, n_s = 32768;
  int cplx = (out_size > 8000000) ? 1 : 0;
  long long o_y = 0, o_xae = n_y, o_xadv = 2 * n_y;
  long long o_yadvr = o_xadv + n_s, o_yadvi = o_yadvr + n_s;
  long long o_kevals = o_yadvi + n_s;
  long long o_kefuns, o_kmodes;
  if (cplx) { o_kefuns = o_kevals + 2 * 8192;  o_kmodes = o_kefuns + 2 * 2097152; }
  else      { o_kefuns = o_kevals + 8192;      o_kmodes = o_kefuns + 2097152; }

  // k1) encoder: y (f32 + f64)
  enc_kernel<<<4096, 256, 0, stream>>>(x,
      ew0, eb0, ew1, eb1, ew2, eb2, ew3, eb3, out + o_y, y64, lim);
  // k2) G = y_m y_m^T, A = y_p y_m^T
  buildGA_kernel<<<128, 256, 0, stream>>>(y64, G, A);
  // k3) K = A G^{-1}
  cholsolve_kernel<<<128, 64, 0, stream>>>(G, A, Km);
  // k4) FAT: eig(K) on blocks 0..127  ||  fp32 x_ae decoder on blocks 128..4223
  eig_dec_kernel<<<128 + 4096, 64, 0, stream>>>(Km, mre, mim, klog,
      out, o_kevals, o_kmodes, cplx, lim,
      y64, dw0, db0, dw1, db1, dw2, db2, dw3, db3, out + o_xae);
  // k5) LU(modes)
  lu_kernel<<<128, 64, 0, stream>>>(mre, mim, lure, luim, piv);
  // k6) k_efuns = modes^{-1} x^T; xint = last column
  lusolve_kernel<<<512, 64, 0, stream>>>(lure, luim, piv, x, out, o_kefuns, cplx,
                                         xint, lim);
  // k7) y_pred scan
  ypred_kernel<<<128, 64, 0, stream>>>(klog, xint, mre, mim, out, o_yadvr, o_yadvi,
                                       yadv, lim);
  // k8) x_adv = decoder(y_adv_real)
  dec4_kernel<<<64, 256, 0, stream>>>(yadv, 512,
      dw0, db0, dw1, db1, dw2, db2, dw3, db3, out + o_xadv, lim);
}

// Round 12
// 4646.863 us; speedup vs baseline: 1.1710x; 1.0949x over previous
//
#include <hip/hip_runtime.h>
#include <hip/hip_bf16.h>

// Problem dims
#define NB 128   // batch
#define NT 256   // time
#define ND 64    // input dim
#define NL 64    // latent dim
#define NH 256   // hidden
#define NP 4     // scan steps

// 30 MiB static device workspace
__device__ double g_ws[3932160];

static __device__ __forceinline__ double dlapy2_(double x, double y) {
  double ax = fabs(x), ay = fabs(y);
  double w = ax > ay ? ax : ay;
  double z = ax > ay ? ay : ax;
  if (z == 0.0) return w;
  double r = z / w;
  return w * sqrt(1.0 + r * r);
}
static __device__ __forceinline__ double sgn1_(double x) { return copysign(1.0, x); }
static __device__ __forceinline__ void cdiv_(double ar, double ai, double br, double bi,
                                             double& cr, double& ci) {
  if (fabs(br) >= fabs(bi)) {
    double r = bi / br, den = br + r * bi;
    cr = (ar + ai * r) / den;
    ci = (ai - ar * r) / den;
  } else {
    double r = br / bi, den = bi + r * br;
    cr = (ar * r + ai) / den;
    ci = (ai * r - ar) / den;
  }
}
static __device__ __forceinline__ void fwg(float* out, long long ofs, long long lim,
                                           double v) {
  if (ofs >= 0 && ofs < lim) out[ofs] = (float)v;
}
// wave-64 reductions (all lanes get the result)
static __device__ __forceinline__ double wsum_(double v) {
  for (int o = 32; o > 0; o >>= 1) v += __shfl_xor(v, o, 64);
  return v;
}
static __device__ __forceinline__ double wmax_(double v) {
  for (int o = 32; o > 0; o >>= 1) v = fmax(v, __shfl_xor(v, o, 64));
  return v;
}
// Single-wave "barrier": DS ops from one wave are processed in order by the LDS
// unit, so cross-lane LDS communication inside a 64-thread block needs only a
// compiler reordering fence. Zero instructions. (Validated R7-R11: correct.)
static __device__ __forceinline__ void wbar() {
  asm volatile("" ::: "memory");
  __builtin_amdgcn_wave_barrier();
  asm volatile("" ::: "memory");
}

// LAPACK dlanv2: standardize a real 2x2 Schur block
static __device__ void dlanv2_(double& a, double& b, double& c, double& d,
                               double& rt1r, double& rt1i, double& rt2r, double& rt2i,
                               double& cs, double& sn) {
  const double eps = 2.2204460492503131e-16;
  if (c == 0.0) {
    cs = 1.0; sn = 0.0;
  } else if (b == 0.0) {
    cs = 0.0; sn = 1.0;
    double temp = d; d = a; a = temp;
    b = -c; c = 0.0;
  } else if ((a - d) == 0.0 && sgn1_(b) != sgn1_(c)) {
    cs = 1.0; sn = 0.0;
  } else {
    double temp = a - d;
    double p = 0.5 * temp;
    double bcmax = fmax(fabs(b), fabs(c));
    double bcmis = fmin(fabs(b), fabs(c)) * sgn1_(b) * sgn1_(c);
    double scale = fmax(fabs(p), bcmax);
    double z = (p / scale) * p + (bcmax / scale) * bcmis;
    if (z >= 4.0 * eps) {
      z = p + copysign(sqrt(scale) * sqrt(z), p);
      a = d + z;
      d = d - (bcmax / z) * bcmis;
      double tau = dlapy2_(c, z);
      cs = z / tau; sn = c / tau;
      b = b - c; c = 0.0;
    } else {
      double sigma = b + c;
      double tau = dlapy2_(sigma, temp);
      cs = sqrt(0.5 * (1.0 + fabs(sigma) / tau));
      sn = -(p / (tau * cs)) * sgn1_(sigma);
      double aa = a * cs + b * sn, bb = -a * sn + b * cs;
      double cc = c * cs + d * sn, dd = -c * sn + d * cs;
      a = aa * cs + cc * sn; b = bb * cs + dd * sn;
      c = -aa * sn + cc * cs; d = -bb * sn + dd * cs;
      temp = 0.5 * (a + d);
      a = temp; d = temp;
      if (c != 0.0) {
        if (b != 0.0) {
          if (sgn1_(b) == sgn1_(c)) {
            double sab = sqrt(fabs(b)), sac = sqrt(fabs(c));
            double p2 = copysign(sab * sac, c);
            double tau2 = 1.0 / sqrt(fabs(b + c));
            a = temp + p2; d = temp - p2;
            b = b - c; c = 0.0;
            double cs1 = sab * tau2, sn1 = sac * tau2;
            double t0 = cs * cs1 - sn * sn1;
            sn = cs * sn1 + sn * cs1;
            cs = t0;
          }
        } else {
          b = -c; c = 0.0;
          double t0 = cs; cs = -sn; sn = t0;
        }
      }
    }
  }
  rt1r = a; rt2r = d;
  if (c == 0.0) { rt1i = 0.0; rt2i = 0.0; }
  else { rt1i = sqrt(fabs(b)) * sqrt(fabs(c)); rt2i = -rt1i; }
}

// ---------------- encoder only: x -> y (f32 out + f64 ws), fp64 math
__global__ __launch_bounds__(256) void enc_kernel(
    const float* __restrict__ x,
    const float* __restrict__ EW0, const float* __restrict__ EB0,
    const float* __restrict__ EW1, const float* __restrict__ EB1,
    const float* __restrict__ EW2, const float* __restrict__ EB2,
    const float* __restrict__ EW3, const float* __restrict__ EB3,
    float* __restrict__ out_y, double* __restrict__ y64, long long lim)
{
  const int tid = threadIdx.x;
  const long long tok0 = (long long)blockIdx.x * 8;
  __shared__ double xin[8][64];
  __shared__ double h0[8][256];
  __shared__ double h1[8][256];
  for (int idx = tid; idx < 512; idx += 256) {
    int tk = idx >> 6, f2 = idx & 63;
    xin[tk][f2] = (double)x[(tok0 + tk) * 64 + f2];
  }
  __syncthreads();
  { // L1 64->256
    int j = tid; double acc[8]; double bj = (double)EB0[j];
    for (int tk = 0; tk < 8; ++tk) acc[tk] = bj;
#pragma unroll 8
    for (int i2 = 0; i2 < 64; ++i2) {
      double w = (double)EW0[i2 * 256 + j];
      for (int tk = 0; tk < 8; ++tk) acc[tk] += xin[tk][i2] * w;
    }
    for (int tk = 0; tk < 8; ++tk) h0[tk][j] = fmax(acc[tk], 0.0);
  }
  __syncthreads();
  { // L2
    int j = tid; double acc[8]; double bj = (double)EB1[j];
    for (int tk = 0; tk < 8; ++tk) acc[tk] = bj;
#pragma unroll 4
    for (int i2 = 0; i2 < 256; ++i2) {
      double w = (double)EW1[i2 * 256 + j];
      for (int tk = 0; tk < 8; ++tk) acc[tk] += h0[tk][i2] * w;
    }
    for (int tk = 0; tk < 8; ++tk) h1[tk][j] = fmax(acc[tk], 0.0);
  }
  __syncthreads();
  { // L3
    int j = tid; double acc[8]; double bj = (double)EB2[j];
    for (int tk = 0; tk < 8; ++tk) acc[tk] = bj;
#pragma unroll 4
    for (int i2 = 0; i2 < 256; ++i2) {
      double w = (double)EW2[i2 * 256 + j];
      for (int tk = 0; tk < 8; ++tk) acc[tk] += h1[tk][i2] * w;
    }
    for (int tk = 0; tk < 8; ++tk) h0[tk][j] = fmax(acc[tk], 0.0);
  }
  __syncthreads();
  { // L4 256->64 (no relu): y
    int j = tid & 63;
    int tg = tid >> 6;
    double acc0 = (double)EB3[j], acc1 = acc0;
#pragma unroll 4
    for (int i2 = 0; i2 < 256; ++i2) {
      double w = (double)EW3[i2 * 64 + j];
      acc0 += h0[tg * 2][i2] * w;
      acc1 += h0[tg * 2 + 1][i2] * w;
    }
    for (int u = 0; u < 2; ++u) {
      int tk = tg * 2 + u;
      double a = (u == 0) ? acc0 : acc1;
      long long gl = (tok0 + tk) * 64 + j;
      fwg(out_y, gl, lim, a);
      y64[gl] = a;
    }
  }
}

// ---------------- standalone 4-layer decoder on f64 input (for x_adv), fp64
__global__ __launch_bounds__(256) void dec4_kernel(
    const double* __restrict__ inp, long long ntok,
    const float* __restrict__ W0, const float* __restrict__ B0,
    const float* __restrict__ W1, const float* __restrict__ B1,
    const float* __restrict__ W2, const float* __restrict__ B2,
    const float* __restrict__ W3, const float* __restrict__ B3,
    float* __restrict__ outb, long long lim)
{
  const int tid = threadIdx.x;
  const long long tok0 = (long long)blockIdx.x * 8;
  __shared__ double xin[8][64];
  __shared__ double h0[8][256];
  __shared__ double h1[8][256];
  for (int idx = tid; idx < 512; idx += 256) {
    int tk = idx >> 6, f2 = idx & 63;
    long long gl = (tok0 + tk) * 64 + f2;
    xin[tk][f2] = (tok0 + tk < ntok) ? inp[gl] : 0.0;
  }
  __syncthreads();
  {
    int j = tid; double acc[8]; double bj = (double)B0[j];
    for (int tk = 0; tk < 8; ++tk) acc[tk] = bj;
#pragma unroll 8
    for (int i2 = 0; i2 < 64; ++i2) {
      double w = (double)W0[i2 * 256 + j];
      for (int tk = 0; tk < 8; ++tk) acc[tk] += xin[tk][i2] * w;
    }
    for (int tk = 0; tk < 8; ++tk) h0[tk][j] = fmax(acc[tk], 0.0);
  }
  __syncthreads();
  {
    int j = tid; double acc[8]; double bj = (double)B1[j];
    for (int tk = 0; tk < 8; ++tk) acc[tk] = bj;
#pragma unroll 4
    for (int i2 = 0; i2 < 256; ++i2) {
      double w = (double)W1[i2 * 256 + j];
      for (int tk = 0; tk < 8; ++tk) acc[tk] += h0[tk][i2] * w;
    }
    for (int tk = 0; tk < 8; ++tk) h1[tk][j] = fmax(acc[tk], 0.0);
  }
  __syncthreads();
  {
    int j = tid; double acc[8]; double bj = (double)B2[j];
    for (int tk = 0; tk < 8; ++tk) acc[tk] = bj;
#pragma unroll 4
    for (int i2 = 0; i2 < 256; ++i2) {
      double w = (double)W2[i2 * 256 + j];
      for (int tk = 0; tk < 8; ++tk) acc[tk] += h1[tk][i2] * w;
    }
    for (int tk = 0; tk < 8; ++tk) h0[tk][j] = fmax(acc[tk], 0.0);
  }
  __syncthreads();
  {
    int j = tid & 63;
    int tg = tid >> 6;
    double acc0 = (double)B3[j], acc1 = acc0;
#pragma unroll 4
    for (int i2 = 0; i2 < 256; ++i2) {
      double w = (double)W3[i2 * 64 + j];
      acc0 += h0[tg * 2][i2] * w;
      acc1 += h0[tg * 2 + 1][i2] * w;
    }
    for (int u = 0; u < 2; ++u) {
      long long tok = tok0 + tg * 2 + u;
      if (tok < ntok) fwg(outb, tok * 64 + j, lim, (u == 0) ? acc0 : acc1);
    }
  }
}

// ---------------- G = y_m y_m^T, A = y_p y_m^T (per batch), fp64
__global__ __launch_bounds__(256) void buildGA_kernel(const double* __restrict__ y64,
                                                      double* __restrict__ G,
                                                      double* __restrict__ A)
{
  int b = blockIdx.x, tid = threadIdx.x;
  __shared__ double ybuf[65][64];
  const double* yb = y64 + (size_t)b * NT * 64;
  double g[16], a[16];
  for (int s = 0; s < 16; ++s) { g[s] = 0.0; a[s] = 0.0; }
  for (int c0 = 0; c0 < 255; c0 += 64) {
    int nrow = (256 - c0 < 65) ? (256 - c0) : 65;
    for (int idx = tid; idx < nrow * 64; idx += 256) {
      int rr = idx >> 6, f2 = idx & 63;
      ybuf[rr][f2] = yb[(size_t)(c0 + rr) * 64 + f2];
    }
    __syncthreads();
    int tmax = (254 - c0 < 63) ? (254 - c0) : 63;
    for (int s = 0; s < 16; ++s) {
      int id = s * 256 + tid;
      int i2 = id >> 6, j2 = id & 63;
      double gg = g[s], aa = a[s];
      for (int tt = 0; tt <= tmax; ++tt) {
        double yj = ybuf[tt][j2];
        gg += ybuf[tt][i2] * yj;
        aa += ybuf[tt + 1][i2] * yj;
      }
      g[s] = gg; a[s] = aa;
    }
    __syncthreads();
  }
  for (int s = 0; s < 16; ++s) {
    int id = s * 256 + tid;
    G[(size_t)b * 4096 + id] = g[s];
    A[(size_t)b * 4096 + id] = a[s];
  }
}

// ---------------- K = A G^{-1} via Cholesky (G SPD), per batch (single wave)
__global__ __launch_bounds__(64) void cholsolve_kernel(const double* __restrict__ G,
                                                       const double* __restrict__ A,
                                                       double* __restrict__ Km)
{
  int b = blockIdx.x, t = threadIdx.x;
  __shared__ double C[64][65];
  __shared__ double X[64][65];
  const double* Gb = G + (size_t)b * 4096;
  const double* Ab = A + (size_t)b * 4096;
  for (int r = 0; r < 64; ++r) C[r][t] = Gb[r * 64 + t];
  for (int i2 = 0; i2 < 64; ++i2) X[i2][t] = Ab[t * 64 + i2];
  __syncthreads();
  for (int k = 0; k < 64; ++k) {
    double s = C[k][k];
    for (int m2 = 0; m2 < k; ++m2) s -= C[k][m2] * C[k][m2];
    double ckk = sqrt(fmax(s, 1e-300));
    wbar();
    if (t == k) C[k][k] = ckk;
    if (t > k) {
      double v = C[t][k];
      for (int m2 = 0; m2 < k; ++m2) v -= C[t][m2] * C[k][m2];
      C[t][k] = v / ckk;
    }
    wbar();
  }
  for (int i2 = 0; i2 < 64; ++i2) {
    double v = X[i2][t];
    for (int m2 = 0; m2 < i2; ++m2) v -= C[i2][m2] * X[m2][t];
    X[i2][t] = v / C[i2][i2];
  }
  for (int i2 = 63; i2 >= 0; --i2) {
    double v = X[i2][t];
    for (int m2 = i2 + 1; m2 < 64; ++m2) v -= C[m2][i2] * X[m2][t];
    X[i2][t] = v / C[i2][i2];
  }
  wbar();
  for (int i2 = 0; i2 < 64; ++i2)
    Km[(size_t)b * 4096 + (size_t)t * 64 + i2] = X[i2][t];
}

// ---------------- FAT kernel: blocks <128 -> eig; blocks >=128 -> fp32 x_ae decoder
__global__ __launch_bounds__(64) void eig_dec_kernel(
    const double* __restrict__ Kmat,
    double* __restrict__ modes_re, double* __restrict__ modes_im,
    double* __restrict__ klog,
    float* __restrict__ out, long long o_kevals, long long o_kmodes,
    int cplx, long long lim,
    const double* __restrict__ y64,
    const float* __restrict__ DW0, const float* __restrict__ DB0,
    const float* __restrict__ DW1, const float* __restrict__ DB1,
    const float* __restrict__ DW2, const float* __restrict__ DB2,
    const float* __restrict__ DW3, const float* __restrict__ DB3,
    float* __restrict__ out_xae)
{
  const int t = threadIdx.x;
  __shared__ __align__(16) double smem[8704];   // 69632 B, shared by both paths

  if (blockIdx.x >= NB) {
    // ---------- fp32 decoder for x_ae, 8 tokens per block ----------
    const int blk = blockIdx.x - NB;
    const long long tok0 = (long long)blk * 8;
    float (*fx)[64] = (float (*)[64])(smem);
    float (*fh0)[256] = (float (*)[256])(smem + 256);
    float (*fh1)[256] = (float (*)[256])(smem + 1280);
    for (int idx = t; idx < 512; idx += 64) {
      int tk = idx >> 6, f2 = idx & 63;
      fx[tk][f2] = (float)y64[(tok0 + tk) * 64 + f2];
    }
    __syncthreads();
    float acc[4][8];
    for (int s = 0; s < 4; ++s) {
      float bj = DB0[t + 64 * s];
      for (int tk = 0; tk < 8; ++tk) acc[s][tk] = bj;
    }
#pragma unroll 4
    for (int i = 0; i < 64; ++i) {
      float xv[8];
      for (int tk = 0; tk < 8; ++tk) xv[tk] = fx[tk][i];
      for (int s = 0; s < 4; ++s) {
        float w = DW0[i * 256 + t + 64 * s];
        for (int tk = 0; tk < 8; ++tk) acc[s][tk] += xv[tk] * w;
      }
    }
    for (int s = 0; s < 4; ++s)
      for (int tk = 0; tk < 8; ++tk) fh0[tk][t + 64 * s] = fmaxf(acc[s][tk], 0.0f);
    __syncthreads();
    for (int s = 0; s < 4; ++s) {
      float bj = DB1[t + 64 * s];
      for (int tk = 0; tk < 8; ++tk) acc[s][tk] = bj;
    }
#pragma unroll 2
    for (int i = 0; i < 256; ++i) {
      float xv[8];
      for (int tk = 0; tk < 8; ++tk) xv[tk] = fh0[tk][i];
      for (int s = 0; s < 4; ++s) {
        float w = DW1[i * 256 + t + 64 * s];
        for (int tk = 0; tk < 8; ++tk) acc[s][tk] += xv[tk] * w;
      }
    }
    for (int s = 0; s < 4; ++s)
      for (int tk = 0; tk < 8; ++tk) fh1[tk][t + 64 * s] = fmaxf(acc[s][tk], 0.0f);
    __syncthreads();
    for (int s = 0; s < 4; ++s) {
      float bj = DB2[t + 64 * s];
      for (int tk = 0; tk < 8; ++tk) acc[s][tk] = bj;
    }
#pragma unroll 2
    for (int i = 0; i < 256; ++i) {
      float xv[8];
      for (int tk = 0; tk < 8; ++tk) xv[tk] = fh1[tk][i];
      for (int s = 0; s < 4; ++s) {
        float w = DW2[i * 256 + t + 64 * s];
        for (int tk = 0; tk < 8; ++tk) acc[s][tk] += xv[tk] * w;
      }
    }
    for (int s = 0; s < 4; ++s)
      for (int tk = 0; tk < 8; ++tk) fh0[tk][t + 64 * s] = fmaxf(acc[s][tk], 0.0f);
    __syncthreads();
    float a4[8];
    float bj3 = DB3[t];
    for (int tk = 0; tk < 8; ++tk) a4[tk] = bj3;
#pragma unroll 2
    for (int i = 0; i < 256; ++i) {
      float w = DW3[i * 64 + t];
      for (int tk = 0; tk < 8; ++tk) a4[tk] += fh0[tk][i] * w;
    }
    for (int tk = 0; tk < 8; ++tk)
      fwg(out_xae, (tok0 + tk) * 64 + t, lim, (double)a4[tk]);
    return;
  }

  // ---------- eig path (blocks 0..127, single wave) ----------
  const int b = blockIdx.x;
  double (*Hs)[65] = (double (*)[65])smem;           // 4160 doubles
  double (*Zs)[65] = (double (*)[65])(smem + 4160);  // 4160 doubles, Zs[col][row]
  double* wr = smem + 8320;
  double* wi = wr + 64;
  double* bscale = wi + 64;
  double* tau = bscale + 64;
  double* xr = tau + 64;
  double* xi = xr + 64;
  double* mre = modes_re + (size_t)b * 4096;  // row-major [row*64+col]
  double* mim = modes_im + (size_t)b * 4096;

  const double ulp = 2.2204460492503131e-16;
  const double safmin = 2.2250738585072014e-308;

  for (int r = 0; r < 64; ++r) Hs[r][t] = Kmat[(size_t)b * 4096 + r * 64 + t];
  bscale[t] = 1.0;
  __syncthreads();

  // ---- dgebal scaling
  {
    const double sclfac = 2.0, factor = 0.95;
    const double sfmin1 = safmin / ulp;
    const double sfmax1 = 1.0 / sfmin1;
    const double sfmin2 = sfmin1 * sclfac;
    const double sfmax2 = 1.0 / sfmin2;
    for (int sweep = 0; sweep < 64; ++sweep) {
      bool noconv = false;
      for (int i = 0; i < 64; ++i) {
        double colv = fabs(Hs[t][i]);
        double rowv = fabs(Hs[i][t]);
        double c = wsum_((t == i) ? 0.0 : colv);
        double r = wsum_((t == i) ? 0.0 : rowv);
        double ca = wmax_(colv);
        double ra = wmax_(rowv);
        if (c == 0.0 || r == 0.0) continue;
        double g = r / sclfac, f = 1.0, s = c + r;
        while (c < g) {
          if (fmax(fmax(f, c), ca) >= sfmax2 || fmin(fmin(r, g), ra) <= sfmin2) break;
          f *= sclfac; c *= sclfac; ca *= sclfac;
          r /= sclfac; g /= sclfac; ra /= sclfac;
        }
        g = c / sclfac;
        while (g >= r) {
          if (fmax(r, ra) >= sfmax2 || fmin(fmin(fmin(f, c), g), ca) <= sfmin2) break;
          f /= sclfac; c /= sclfac; g /= sclfac; ca /= sclfac;
          r *= sclfac; ra *= sclfac;
        }
        if (c + r >= factor * s) continue;
        double bsi = bscale[i];
        if (f < 1.0 && bsi < 1.0) { if (f * bsi <= sfmin1) continue; }
        if (f > 1.0 && bsi > 1.0) { if (bsi >= sfmax1 / f) continue; }
        double gi = 1.0 / f;
        Hs[i][t] *= gi;
        Hs[t][i] *= f;
        if (t == 0) bscale[i] = bsi * f;
        noconv = true;
        wbar();
      }
      if (!noconv) break;
    }
    wbar();
  }

  // ---- dgehd2
  for (int i = 0; i < 62; ++i) {
    double alpha = Hs[i + 1][i];
    double contrib = (t >= i + 2) ? Hs[t][i] * Hs[t][i] : 0.0;
    double ss = wsum_(contrib);
    double taui, beta;
    if (ss == 0.0) {
      taui = 0.0; beta = alpha;
    } else {
      beta = -copysign(sqrt(alpha * alpha + ss), alpha);
      taui = (beta - alpha) / beta;
      double sc = 1.0 / (alpha - beta);
      if (t >= i + 2) Hs[t][i] *= sc;
    }
    if (t == 0) { tau[i] = taui; Hs[i + 1][i] = beta; }
    wbar();
    if (taui != 0.0) {
      {
        double sum = Hs[t][i + 1];
        for (int k = i + 2; k < 64; ++k) sum += Hs[t][k] * Hs[k][i];
        sum *= taui;
        Hs[t][i + 1] -= sum;
        for (int k = i + 2; k < 64; ++k) Hs[t][k] -= sum * Hs[k][i];
      }
      wbar();
      if (t >= i + 1) {
        double sum = Hs[i + 1][t];
        for (int k = i + 2; k < 64; ++k) sum += Hs[k][i] * Hs[k][t];
        sum *= taui;
        Hs[i + 1][t] -= sum;
        for (int k = i + 2; k < 64; ++k) Hs[k][t] -= sum * Hs[k][i];
      }
      wbar();
    }
  }

  // ---- dorghr: Zs[col][row], lane t owns column t
  {
    for (int r = 0; r < 64; ++r) Zs[t][r] = (r == t) ? 1.0 : 0.0;
    for (int i = 61; i >= 0; --i) {
      double taui = tau[i];
      if (taui != 0.0) {
        double sum = Zs[t][i + 1];
        for (int k = i + 2; k < 64; ++k) sum += Hs[k][i] * Zs[t][k];
        sum *= taui;
        Zs[t][i + 1] -= sum;
        for (int k = i + 2; k < 64; ++k) Zs[t][k] -= sum * Hs[k][i];
      }
    }
  }
  wbar();
  for (int r = t + 2; r < 64; ++r) Hs[r][t] = 0.0;
  __syncthreads();

  // ---- dlahqr (wantt, wantz)
  {
    const int lo = 0, hi = 63;
    const double dat1 = 0.75, dat2 = -0.4375;
    const int kexsh = 10;
    const double smlnum = safmin * (64.0 / ulp);
    int I = hi;
    int kdefl = 0;
    while (I >= lo) {
      int L = lo;
      bool done = false;
      const int itmax = 30 * 64;
      for (int its = 0; its <= itmax; ++its) {
        int k;
        {
          bool pred = false;
          int kl = t;
          if (kl > L && kl <= I) {
            double sub = fabs(Hs[kl][kl - 1]);
            if (sub <= smlnum) pred = true;
            else {
              double tst = fabs(Hs[kl - 1][kl - 1]) + fabs(Hs[kl][kl]);
              if (tst == 0.0) {
                if (kl - 2 >= lo) tst += fabs(Hs[kl - 1][kl - 2]);
                if (kl + 1 <= hi) tst += fabs(Hs[kl + 1][kl]);
              }
              if (sub <= ulp * tst) {
                double h12a = fabs(Hs[kl - 1][kl]);
                double ab = fmax(sub, h12a), ba = fmin(sub, h12a);
                double hkk = fabs(Hs[kl][kl]);
                double dif = fabs(Hs[kl - 1][kl - 1] - Hs[kl][kl]);
                double aa = fmax(hkk, dif), bb2 = fmin(hkk, dif);
                double s = aa + ab;
                if (ba * (ab / s) <= fmax(smlnum, ulp * (bb2 * (aa / s)))) pred = true;
              }
            }
          }
          unsigned long long msk = __ballot(pred);
          k = msk ? (63 - __builtin_clzll(msk)) : L;
        }
        L = k;
        if (L > lo) { if (t == 0) Hs[L][L - 1] = 0.0; }
        wbar();
        if (L >= I - 1) { done = true; break; }
        kdefl++;
        double h11, h12, h21, h22;
        if (kdefl % (2 * kexsh) == 0) {
          double s = dat1 * (fabs(Hs[I][I - 1]) + fabs(Hs[I - 1][I - 2]));
          h11 = dat2 * s + Hs[I][I]; h12 = s; h21 = s; h22 = h11;
        } else if (kdefl % kexsh == 0) {
          double s = dat1 * (fabs(Hs[L + 1][L]) + fabs(Hs[L + 2][L + 1]));
          h11 = dat2 * s + Hs[L][L]; h12 = s; h21 = s; h22 = h11;
        } else {
          h11 = Hs[I - 1][I - 1]; h21 = Hs[I][I - 1];
          h12 = Hs[I - 1][I];     h22 = Hs[I][I];
        }
        double rt1r, rt1i, rt2r, rt2i;
        {
          double s = fabs(h11) + fabs(h12) + fabs(h21) + fabs(h22);
          if (s == 0.0) { rt1r = rt1i = rt2r = rt2i = 0.0; }
          else {
            double a_ = h11 / s, c_ = h21 / s, b_ = h12 / s, d_ = h22 / s;
            double tr = a_ + d_;
            double det = (a_ - d_) * (a_ - d_) * 0.25 + b_ * c_;
            if (det >= 0.0) {
              double rtdisc = sqrt(det);
              double r1 = tr * 0.5 + rtdisc;
              double r2 = tr * 0.5 - rtdisc;
              double pick = (fabs(r1 - d_) <= fabs(r2 - d_)) ? r1 : r2;
              rt1r = pick * s; rt2r = rt1r; rt1i = 0.0; rt2i = 0.0;
            } else {
              rt1r = tr * 0.5 * s; rt2r = rt1r;
              rt1i = sqrt(-det) * s; rt2i = -rt1i;
            }
          }
        }
        int m; double v0, v1, v2;
        {
          double w0 = 0.0, w1 = 0.0, w2 = 0.0;
          bool ok = false;
          int mm = t;
          if (mm >= L && mm <= I - 2) {
            double h21s = Hs[mm + 1][mm];
            double s = fabs(Hs[mm][mm] - rt2r) + fabs(rt2i) + fabs(h21s);
            h21s = Hs[mm + 1][mm] / s;
            w0 = h21s * Hs[mm][mm + 1] + (Hs[mm][mm] - rt1r) * ((Hs[mm][mm] - rt2r) / s)
                 - rt1i * (rt2i / s);
            w1 = h21s * (Hs[mm][mm] + Hs[mm + 1][mm + 1] - rt1r - rt2r);
            w2 = h21s * Hs[mm + 2][mm + 1];
            double s2 = fabs(w0) + fabs(w1) + fabs(w2);
            w0 /= s2; w1 /= s2; w2 /= s2;
            if (mm == L) ok = true;
            else ok = (fabs(Hs[mm][mm - 1]) * (fabs(w1) + fabs(w2)) <=
                       ulp * fabs(w0) *
                           (fabs(Hs[mm - 1][mm - 1]) + fabs(Hs[mm][mm]) +
                            fabs(Hs[mm + 1][mm + 1])));
          }
          unsigned long long msk = __ballot(ok);
          m = 63 - __builtin_clzll(msk);
          v0 = __shfl(w0, m); v1 = __shfl(w1, m); v2 = __shfl(w2, m);
        }
        // ---- bulge chase (R9 structure: row preloads + Z register carry)
        double c0 = 0.0, c1 = 0.0, c2 = 0.0;
        double zc0 = 0.0, zc1 = 0.0;
        for (int kk = m; kk <= I - 1; ++kk) {
          int nr = (3 < I - kk + 1) ? 3 : (I - kk + 1);
          // row preloads: phase A is the first toucher of rows kk..kk+2 this
          // step, so these reads are off the intra-step dependency chain and
          // their latency hides under dlarfg.
          double a0 = Hs[kk][t];
          double a1 = Hs[kk + 1][t];
          double a2 = (nr == 3) ? Hs[kk + 2][t] : 0.0;
          // Z: rows kk,kk+1 were written by THIS lane last step -> register carry
          double z0, z1;
          if (kk > m) { z0 = zc0; z1 = zc1; }
          else { z0 = Zs[kk][t]; z1 = Zs[kk + 1][t]; }
          double z2 = (nr == 3) ? Zs[kk + 2][t] : 0.0;
          double u0, u1, u2 = 0.0;
          if (kk > m) { u0 = c0; u1 = c1; u2 = (nr == 3) ? c2 : 0.0; }
          else        { u0 = v0; u1 = v1; u2 = (nr == 3) ? v2 : 0.0; }
          double t1;
          {  // dlarfg, plain sqrt
            double xn2 = u1 * u1 + u2 * u2;
            if (xn2 == 0.0) t1 = 0.0;
            else {
              double beta = -copysign(sqrt(u0 * u0 + xn2), u0);
              t1 = (beta - u0) / beta;
              double sc = 1.0 / (u0 - beta);
              u1 *= sc; u2 *= sc;
              u0 = beta;
            }
          }
          double t2 = t1 * u1, t3 = t1 * u2;
          // phase A: left(row) update from preloaded values + reflector storage
          if (t >= kk) {
            double sum = a0 + u1 * a1 + u2 * a2;
            Hs[kk][t] = a0 - sum * t1;
            Hs[kk + 1][t] = a1 - sum * t2;
            if (nr == 3) Hs[kk + 2][t] = a2 - sum * t3;
          }
          if (t == 0) {
            if (kk > m) {
              Hs[kk][kk - 1] = u0;
              Hs[kk + 1][kk - 1] = 0.0;
              if (kk < I - 1) Hs[kk + 2][kk - 1] = 0.0;
            } else if (m > L) {
              Hs[kk][kk - 1] *= (1.0 - t1);
            }
          }
          wbar();
          // phase B: right(col) update (reads after fence) + Z from regs
          int rmax = (kk + 3 < I) ? kk + 3 : I;
          double nv0 = 0.0;
          if (t <= rmax) {
            double b0 = Hs[t][kk], b1 = Hs[t][kk + 1];
            double b2 = (nr == 3) ? Hs[t][kk + 2] : 0.0;
            double sB = b0 + u1 * b1 + u2 * b2;
            nv0 = b0 - sB * t1;
            Hs[t][kk] = nv0;
            Hs[t][kk + 1] = b1 - sB * t2;
            if (nr == 3) Hs[t][kk + 2] = b2 - sB * t3;
          }
          {
            double sZ = z0 + u1 * z1 + u2 * z2;
            Zs[kk][t] = z0 - sZ * t1;
            zc0 = z1 - sZ * t2;
            Zs[kk + 1][t] = zc0;
            if (nr == 3) {
              zc1 = z2 - sZ * t3;
              Zs[kk + 2][t] = zc1;
            }
          }
          int s1 = (kk + 1 < 64) ? kk + 1 : 63;
          int s2 = (kk + 2 < 64) ? kk + 2 : 63;
          int s3 = (kk + 3 < 64) ? kk + 3 : 63;
          c0 = __shfl(nv0, s1, 64);
          c1 = __shfl(nv0, s2, 64);
          c2 = __shfl(nv0, s3, 64);
          wbar();
        }
      } // its
      if (!done) {  // failsafe
        wbar();
        if (t == 0) {
          for (int r = lo; r <= I; ++r) { wr[r] = Hs[r][r]; wi[r] = 0.0; }
        }
        wbar();
        I = lo - 1;
        kdefl = 0;
        continue;
      }
      if (L == I) {
        if (t == 0) { wr[I] = Hs[I][I]; wi[I] = 0.0; }
        wbar();
      } else {  // 2x2 block: dlanv2 + rotations
        double a_ = Hs[I - 1][I - 1], b_ = Hs[I - 1][I];
        double c_ = Hs[I][I - 1],     d_ = Hs[I][I];
        double r1r, r1i, r2r, r2i, cs, sn;
        dlanv2_(a_, b_, c_, d_, r1r, r1i, r2r, r2i, cs, sn);
        wbar();
        if (t == 0) {
          Hs[I - 1][I - 1] = a_; Hs[I - 1][I] = b_;
          Hs[I][I - 1] = c_;     Hs[I][I] = d_;
          wr[I - 1] = r1r; wi[I - 1] = r1i;
          wr[I] = r2r;     wi[I] = r2i;
        }
        wbar();
        if (t > I) {
          double x = Hs[I - 1][t], y = Hs[I][t];
          Hs[I - 1][t] = cs * x + sn * y;
          Hs[I][t] = cs * y - sn * x;
        }
        if (t < I - 1) {
          double x = Hs[t][I - 1], y = Hs[t][I];
          Hs[t][I - 1] = cs * x + sn * y;
          Hs[t][I] = cs * y - sn * x;
        }
        {
          double x = Zs[I - 1][t], y = Zs[I][t];
          Zs[I - 1][t] = cs * x + sn * y;
          Zs[I][t] = cs * y - sn * x;
        }
        wbar();
      }
      kdefl = 0;
      I = L - 1;
    }
  }
  __syncthreads();

  // ---- dtrevc + dgebak + normalization
  const double smln = safmin * (64.0 / ulp);
  int ki = 63;
  while (ki >= 0) {
    wbar();
    bool pair = (ki > 0) && (Hs[ki][ki - 1] != 0.0);
    if (!pair) {
      double lam = wr[ki];
      double smin = fmax(ulp * fabs(lam), smln);
      xr[t] = (t < ki) ? -Hs[t][ki] : ((t == ki) ? 1.0 : 0.0);
      wbar();
      int j = ki - 1;
      while (j >= 0) {
        bool blk2 = (j > 0) && (Hs[j][j - 1] != 0.0);
        if (!blk2) {
          double den = Hs[j][j] - lam;
          if (fabs(den) < smin) den = smin;
          double xj = xr[j] / den;
          if (t == j) xr[j] = xj;
          else if (t < j) xr[t] -= xj * Hs[t][j];
          wbar();
          j -= 1;
        } else {
          double t11 = Hs[j - 1][j - 1] - lam, t12 = Hs[j - 1][j];
          double t21 = Hs[j][j - 1], t22 = Hs[j][j] - lam;
          double det = t11 * t22 - t12 * t21;
          if (fabs(det) < smin * smin) det = copysign(smin * smin, (det == 0.0) ? 1.0 : det);
          double b1 = xr[j - 1], b2 = xr[j];
          double x1 = (b1 * t22 - t12 * b2) / det;
          double x2 = (t11 * b2 - t21 * b1) / det;
          if (t == j - 1) xr[j - 1] = x1;
          else if (t == j) xr[j] = x2;
          else if (t < j - 1) xr[t] -= x1 * Hs[t][j - 1] + x2 * Hs[t][j];
          wbar();
          j -= 2;
        }
      }
      double acc = 0.0;
      for (int k2 = 0; k2 <= ki; ++k2) acc += Zs[k2][t] * xr[k2];
      acc *= bscale[t];
      double nn = wsum_(acc * acc);
      double scl = 1.0 / sqrt(nn);
      mre[t * 64 + ki] = acc * scl;
      mim[t * 64 + ki] = 0.0;
      ki -= 1;
    } else {
      double wre = Hs[ki][ki];
      double wim = sqrt(fabs(Hs[ki][ki - 1])) * sqrt(fabs(Hs[ki - 1][ki]));
      double smin = fmax(ulp * (fabs(wre) + wim), smln);
      double seed_r_km1, seed_i_k;
      if (fabs(Hs[ki - 1][ki]) >= fabs(Hs[ki][ki - 1])) {
        seed_r_km1 = 1.0;
        seed_i_k = wim / Hs[ki - 1][ki];
      } else {
        seed_r_km1 = -wim / Hs[ki][ki - 1];
        seed_i_k = 1.0;
      }
      if (t < ki - 1) {
        xr[t] = -seed_r_km1 * Hs[t][ki - 1];
        xi[t] = -seed_i_k * Hs[t][ki];
      } else if (t == ki - 1) { xr[t] = seed_r_km1; xi[t] = 0.0; }
      else if (t == ki) { xr[t] = 0.0; xi[t] = seed_i_k; }
      else { xr[t] = 0.0; xi[t] = 0.0; }
      wbar();
      int j = ki - 2;
      while (j >= 0) {
        bool blk2 = (j > 0) && (Hs[j][j - 1] != 0.0);
        if (!blk2) {
          double dr = Hs[j][j] - wre, di = -wim;
          if (fabs(dr) + fabs(di) < smin) { dr = smin; di = 0.0; }
          double xjr, xji;
          cdiv_(xr[j], xi[j], dr, di, xjr, xji);
          if (t == j) { xr[j] = xjr; xi[j] = xji; }
          else if (t < j) {
            xr[t] -= xjr * Hs[t][j];
            xi[t] -= xji * Hs[t][j];
          }
          wbar();
          j -= 1;
        } else {
          double t11 = Hs[j - 1][j - 1] - wre, t12 = Hs[j - 1][j];
          double t21 = Hs[j][j - 1], t22 = Hs[j][j] - wre;
          double detr = t11 * t22 - wim * wim - t12 * t21;
          double deti = -wim * (t11 + t22);
          double b1r = xr[j - 1], b1i = xi[j - 1];
          double b2r = xr[j], b2i = xi[j];
          double n1r = b1r * t22 + b1i * wim - t12 * b2r;
          double n1i = b1i * t22 - b1r * wim - t12 * b2i;
          double n2r = t11 * b2r + b2i * wim - t21 * b1r;
          double n2i = t11 * b2i - b2r * wim - t21 * b1i;
          double x1r, x1i, x2r, x2i;
          cdiv_(n1r, n1i, detr, deti, x1r, x1i);
          cdiv_(n2r, n2i, detr, deti, x2r, x2i);
          if (t == j - 1) { xr[t] = x1r; xi[t] = x1i; }
          else if (t == j) { xr[t] = x2r; xi[t] = x2i; }
          else if (t < j - 1) {
            xr[t] -= x1r * Hs[t][j - 1] + x2r * Hs[t][j];
            xi[t] -= x1i * Hs[t][j - 1] + x2i * Hs[t][j];
          }
          wbar();
          j -= 2;
        }
      }
      double ar = 0.0, ai = 0.0;
      for (int k2 = 0; k2 <= ki; ++k2) {
        double z = Zs[k2][t];
        ar += z * xr[k2];
        ai += z * xi[k2];
      }
      ar *= bscale[t]; ai *= bscale[t];
      double n2a = wsum_(ar * ar), n2b = wsum_(ai * ai);
      double scl = 1.0 / dlapy2_(sqrt(n2a), sqrt(n2b));
      double vr0 = ar * scl, vi0 = ai * scl;
      double mm = vr0 * vr0 + vi0 * vi0;
      double mmax = wmax_(mm);
      unsigned long long msk = __ballot(mm == mmax);
      int kmx = __ffsll((unsigned long long)msk) - 1;
      double f = __shfl(vr0, kmx), g = __shfl(vi0, kmx);
      double cs_, sn_;
      if (g == 0.0) { cs_ = 1.0; sn_ = 0.0; }
      else if (f == 0.0) { cs_ = 0.0; sn_ = sgn1_(g); }
      else {
        double dd = sqrt(f * f + g * g);
        double sg = sgn1_(f);
        cs_ = fabs(f) / dd;
        sn_ = sg * g / dd;
      }
      double nr0 = cs_ * vr0 + sn_ * vi0;
      double ni0 = cs_ * vi0 - sn_ * vr0;
      if (t == kmx) ni0 = 0.0;
      mre[t * 64 + (ki - 1)] = nr0;
      mim[t * 64 + (ki - 1)] = ni0;
      mre[t * 64 + ki] = nr0;
      mim[t * 64 + ki] = -ni0;
      ki -= 2;
    }
  }

  // ---- k_evals = log(lambda) and outputs
  {
    double er = wr[t], ei = wi[t];
    double lr = log(dlapy2_(er, ei));
    double li = atan2(ei, er);
    klog[(size_t)b * 128 + 2 * t] = lr;
    klog[(size_t)b * 128 + 2 * t + 1] = li;
    if (cplx) {
      fwg(out, o_kevals + ((long long)b * 64 + t) * 2, lim, lr);
      fwg(out, o_kevals + ((long long)b * 64 + t) * 2 + 1, lim, li);
    } else {
      fwg(out, o_kevals + (long long)b * 64 + t, lim, lr);
    }
  }
  for (int k2 = 0; k2 < 64; ++k2) {
    long long idx = ((long long)b * 64 + t) * 64 + k2;
    if (cplx) {
      fwg(out, o_kmodes + idx * 2, lim, mre[t * 64 + k2]);
      fwg(out, o_kmodes + idx * 2 + 1, lim, mim[t * 64 + k2]);
    } else {
      fwg(out, o_kmodes + idx, lim, mre[t * 64 + k2]);
    }
  }
}

// ---------------- complex LU with |re|+|im| partial pivoting (single wave)
__global__ __launch_bounds__(64) void lu_kernel(
    const double* __restrict__ mre, const double* __restrict__ mim,
    double* __restrict__ lure, double* __restrict__ luim, int* __restrict__ piv)
{
  int b = blockIdx.x, t = threadIdx.x;
  __shared__ double Lre[64][65], Lim[64][65];
  for (int r = 0; r < 64; ++r) {
    Lre[r][t] = mre[(size_t)b * 4096 + r * 64 + t];
    Lim[r][t] = mim[(size_t)b * 4096 + r * 64 + t];
  }
  __syncthreads();
  for (int k = 0; k < 64; ++k) {
    double mval = (t >= k) ? (fabs(Lre[t][k]) + fabs(Lim[t][k])) : -1.0;
    double mmax = wmax_(mval);
    unsigned long long msk = __ballot(mval == mmax);
    int p = __ffsll(msk) - 1;
    if (t == 0) piv[b * 64 + k] = p;
    if (p != k) {
      double a0 = Lre[k][t], a1 = Lim[k][t];
      Lre[k][t] = Lre[p][t]; Lim[k][t] = Lim[p][t];
      Lre[p][t] = a0; Lim[p][t] = a1;
    }
    wbar();
    double pr = Lre[k][k], pi = Lim[k][k];
    if (t > k) {
      double lr, li;
      cdiv_(Lre[t][k], Lim[t][k], pr, pi, lr, li);
      Lre[t][k] = lr; Lim[t][k] = li;
      for (int c = k + 1; c < 64; ++c) {
        double ur = Lre[k][c], ui = Lim[k][c];
        Lre[t][c] -= lr * ur - li * ui;
        Lim[t][c] -= lr * ui + li * ur;
      }
    }
    wbar();
  }
  for (int r = 0; r < 64; ++r) {
    lure[(size_t)b * 4096 + r * 64 + t] = Lre[r][t];
    luim[(size_t)b * 4096 + r * 64 + t] = Lim[r][t];
  }
}

// ---------------- solve modes * X = x^T per batch (256 RHS, 4 chunks of 64)
__global__ __launch_bounds__(64) void lusolve_kernel(
    const double* __restrict__ lure, const double* __restrict__ luim,
    const int* __restrict__ piv, const float* __restrict__ x_in,
    float* __restrict__ out, long long o_kefuns, int cplx,
    double* __restrict__ xint, long long lim)
{
  int b = blockIdx.x >> 2;
  int chunk = blockIdx.x & 3;
  int t = threadIdx.x;
  int tglob = chunk * 64 + t;
  __shared__ double br_[64][64], bi_[64][64];
  const double* Lr = lure + (size_t)b * 4096;
  const double* Li = luim + (size_t)b * 4096;
  for (int i2 = 0; i2 < 64; ++i2) {
    br_[i2][t] = (double)x_in[((size_t)b * 256 + tglob) * 64 + i2];
    bi_[i2][t] = 0.0;
  }
  const int* pv = piv + b * 64;
  for (int k = 0; k < 64; ++k) {
    int p = pv[k];
    if (p != k) {
      double a0 = br_[k][t], a1 = bi_[k][t];
      br_[k][t] = br_[p][t]; bi_[k][t] = bi_[p][t];
      br_[p][t] = a0; bi_[p][t] = a1;
    }
  }
  for (int k = 0; k < 63; ++k) {
    double bkr = br_[k][t], bki = bi_[k][t];
    for (int i2 = k + 1; i2 < 64; ++i2) {
      double lr = Lr[i2 * 64 + k], li = Li[i2 * 64 + k];
      br_[i2][t] -= lr * bkr - li * bki;
      bi_[i2][t] -= lr * bki + li * bkr;
    }
  }
  for (int k = 63; k >= 0; --k) {
    double xr0, xi0;
    cdiv_(br_[k][t], bi_[k][t], Lr[k * 64 + k], Li[k * 64 + k], xr0, xi0);
    br_[k][t] = xr0; bi_[k][t] = xi0;
    for (int i2 = 0; i2 < k; ++i2) {
      double ur = Lr[i2 * 64 + k], ui = Li[i2 * 64 + k];
      br_[i2][t] -= ur * xr0 - ui * xi0;
      bi_[i2][t] -= ur * xi0 + ui * xr0;
    }
  }
  for (int i2 = 0; i2 < 64; ++i2) {
    long long idx = ((long long)b * 64 + i2) * 256 + tglob;
    if (cplx) {
      fwg(out, o_kefuns + idx * 2, lim, br_[i2][t]);
      fwg(out, o_kefuns + idx * 2 + 1, lim, bi_[i2][t]);
    } else {
      fwg(out, o_kefuns + idx, lim, br_[i2][t]);
    }
  }
  if (tglob == 255) {
    for (int i2 = 0; i2 < 64; ++i2) {
      xint[(size_t)b * 128 + 2 * i2] = br_[i2][t];
      xint[(size_t)b * 128 + 2 * i2 + 1] = bi_[i2][t];
    }
  }
}

// ---------------- y_pred scan
__global__ __launch_bounds__(64) void ypred_kernel(
    const double* __restrict__ klog, const double* __restrict__ xint,
    const double* __restrict__ mre, const double* __restrict__ mim,
    float* __restrict__ out, long long o_yadvr, long long o_yadvi,
    double* __restrict__ yadv64, long long lim)
{
  int b = blockIdx.x, t = threadIdx.x;
  __shared__ double er[64], ei[64], wxr[64], wxi[64];
  double kr = klog[(size_t)b * 128 + 2 * t], kiv = klog[(size_t)b * 128 + 2 * t + 1];
  er[t] = kr * kr - kiv * kiv;
  ei[t] = 2.0 * kr * kiv;
  double xr0 = xint[(size_t)b * 128 + 2 * t], xi0 = xint[(size_t)b * 128 + 2 * t + 1];
  __syncthreads();
  for (int p = 0; p < 4; ++p) {
    wxr[t] = er[t] * xr0 - ei[t] * xi0;
    wxi[t] = er[t] * xi0 + ei[t] * xr0;
    __syncthreads();
    double ar = 0.0, ai = 0.0;
    const double* mr = mre + (size_t)b * 4096 + (size_t)t * 64;
    const double* mi = mim + (size_t)b * 4096 + (size_t)t * 64;
    for (int k = 0; k < 64; ++k) {
      double wr0 = wxr[k], wi0 = wxi[k];
      ar += mr[k] * wr0 - mi[k] * wi0;
      ai += mr[k] * wi0 + mi[k] * wr0;
    }
    long long idx = ((long long)b * 4 + p) * 64 + t;
    fwg(out, o_yadvr + idx, lim, ar);
    fwg(out, o_yadvi + idx, lim, ai);
    yadv64[idx] = ar;
    double e2r = er[t] * er[t] - ei[t] * ei[t];
    double e2i = 2.0 * er[t] * ei[t];
    __syncthreads();
    er[t] = e2r; ei[t] = e2i;
    __syncthreads();
  }
}

extern "C" void kernel_launch(void* const* d_in, const int* in_sizes, int n_in,
                              void* d_out, int out_size, void* d_ws, size_t ws_size,
                              hipStream_t stream) {
  (void)in_sizes; (void)n_in; (void)d_ws; (void)ws_size;
  const float* x = (const float*)d_in[0];
  const float* ew0 = (const float*)d_in[1];  const float* eb0 = (const float*)d_in[2];
  const float* ew1 = (const float*)d_in[3];  const float* eb1 = (const float*)d_in[4];
  const float* ew2 = (const float*)d_in[5];  const float* eb2 = (const float*)d_in[6];
  const float* ew3 = (const float*)d_in[7];  const float* eb3 = (const float*)d_in[8];
  const float* dw0 = (const float*)d_in[9];  const float* db0 = (const float*)d_in[10];
  const float* dw1 = (const float*)d_in[11]; const float* db1 = (const float*)d_in[12];
  const float* dw2 = (const float*)d_in[13]; const float* db2 = (const float*)d_in[14];
  const float* dw3 = (const float*)d_in[15]; const float* db3 = (const float*)d_in[16];
  float* out = (float*)d_out;   // output dtype is FLOAT32
  const long long lim = (long long)out_size;

  void* wsp = nullptr;
  hipGetSymbolAddress(&wsp, HIP_SYMBOL(g_ws));
  char* ws = (char*)wsp;
  // Alias audit (per-kernel live sets, all disjoint):
  double* y64  = (double*)(ws + 0);            // [0,16M)   k1 -> eig_dec(decoder)
  double* G    = (double*)(ws + 16777216);     // [16,20M)  k2 -> k3
  double* A    = (double*)(ws + 20971520);     // [20,24M)  k2 -> k3
  double* Km   = (double*)(ws + 25165824);     // [24,28M)  k3 -> k4
  double* mre  = (double*)(ws + 16777216);     // [16,20M)  k4 -> k7 (G dead)
  double* mim  = (double*)(ws + 20971520);     // [20,24M)  k4 -> k7 (A dead)
  double* lure = (double*)(ws + 25165824);     // [24,28M)  k5 -> k6 (Km dead)
  double* luim = (double*)(ws + 0);            // [0,4M)    k5 -> k6 (y64 dead)
  double* klog = (double*)(ws + 29360128);     // +128K     k4 -> k7
  double* xint = (double*)(ws + 29491200);     // +128K     k6 -> k7
  double* yadv = (double*)(ws + 29622272);     // +256K     k7 -> k8
  int*    piv  = (int*)   (ws + 29884416);     // +32K      k5 -> k6

  const long long n_y = 2097152, n_s = 32768;
  int cplx = (out_size > 8000000) ? 1 : 0;
  long long o_y = 0, o_xae = n_y, o_xadv = 2 * n_y;
  long long o_yadvr = o_xadv + n_s, o_yadvi = o_yadvr + n_s;
  long long o_kevals = o_yadvi + n_s;
  long long o_kefuns, o_kmodes;
  if (cplx) { o_kefuns = o_kevals + 2 * 8192;  o_kmodes = o_kefuns + 2 * 2097152; }
  else      { o_kefuns = o_kevals + 8192;      o_kmodes = o_kefuns + 2097152; }

  // k1) encoder: y (f32 + f64)
  enc_kernel<<<4096, 256, 0, stream>>>(x,
      ew0, eb0, ew1, eb1, ew2, eb2, ew3, eb3, out + o_y, y64, lim);
  // k2) G = y_m y_m^T, A = y_p y_m^T
  buildGA_kernel<<<128, 256, 0, stream>>>(y64, G, A);
  // k3) K = A G^{-1}
  cholsolve_kernel<<<128, 64, 0, stream>>>(G, A, Km);
  // k4) FAT: eig(K) on blocks 0..127  ||  fp32 x_ae decoder on blocks 128..4223
  eig_dec_kernel<<<128 + 4096, 64, 0, stream>>>(Km, mre, mim, klog,
      out, o_kevals, o_kmodes, cplx, lim,
      y64, dw0, db0, dw1, db1, dw2, db2, dw3, db3, out + o_xae);
  // k5) LU(modes)
  lu_kernel<<<128, 64, 0, stream>>>(mre, mim, lure, luim, piv);
  // k6) k_efuns = modes^{-1} x^T; xint = last column
  lusolve_kernel<<<512, 64, 0, stream>>>(lure, luim, piv, x, out, o_kefuns, cplx,
                                         xint, lim);
  // k7) y_pred scan
  ypred_kernel<<<128, 64, 0, stream>>>(klog, xint, mre, mim, out, o_yadvr, o_yadvi,
                                       yadv, lim);
  // k8) x_adv = decoder(y_adv_real)
  dec4_kernel<<<64, 256, 0, stream>>>(yadv, 512,
      dw0, db0, dw1, db1, dw2, db2, dw3, db3, out + o_xadv, lim);
}